// Round 2
// baseline (474.575 us; speedup 1.0000x reference)
//
#include <hip/hip_runtime.h>
#include <stdint.h>
#include <stddef.h>

typedef __bf16 bf16_t;
typedef bf16_t bf16x4 __attribute__((ext_vector_type(4)));
typedef bf16_t bf16x8 __attribute__((ext_vector_type(8)));
typedef float  f32x4  __attribute__((ext_vector_type(4)));
typedef _Float16 f16_t;
typedef f16_t f16x2 __attribute__((ext_vector_type(2)));
typedef f16_t f16x4 __attribute__((ext_vector_type(4)));
typedef f16_t f16x8 __attribute__((ext_vector_type(8)));
typedef __fp16 fp16x2_raw __attribute__((ext_vector_type(2)));   // cvt_pkrtz native type

__device__ __forceinline__ f16x2 pkrtz(float a, float b) {
    fp16x2_raw r = __builtin_amdgcn_cvt_pkrtz(a, b);
    union { fp16x2_raw r; f16x2 h; } u;
    u.r = r;
    return u.h;
}

#define MFMA_BF16_K32(a, b, c) __builtin_amdgcn_mfma_f32_16x16x32_bf16(a, b, c, 0, 0, 0)
#define MFMA_F16_K32(a, b, c)  __builtin_amdgcn_mfma_f32_16x16x32_f16(a, b, c, 0, 0, 0)

// ---------------------------------------------------------------- helpers
__device__ __forceinline__ void gload_lds16(const void* g, void* l) {
    __builtin_amdgcn_global_load_lds(
        (const __attribute__((address_space(1))) void*)g,
        (__attribute__((address_space(3))) void*)l,
        16, 0, 0);
}

// ---------------------------------------------------------------- fused fp32 -> bf16 casts
#define NX 1572864           // x  float4 count
#define NWA 442368           // Wa float4 count
#define NWP 147456           // Wp float4 count
__global__ void cvt_all(const float* __restrict__ x, const float* __restrict__ Wa,
                        const float* __restrict__ Wp, bf16_t* __restrict__ xb,
                        bf16_t* __restrict__ Wab, bf16_t* __restrict__ Wpb) {
    int i = blockIdx.x * blockDim.x + threadIdx.x;
    const float4* src; bf16_t* dst; int j;
    if (i < NX)            { src = (const float4*)x;  dst = xb;  j = i; }
    else if (i < NX + NWA) { src = (const float4*)Wa; dst = Wab; j = i - NX; }
    else                   { src = (const float4*)Wp; dst = Wpb; j = i - NX - NWA; }
    float4 f = src[j];
    bf16x4 o = { (bf16_t)f.x, (bf16_t)f.y, (bf16_t)f.z, (bf16_t)f.w };
    ((bf16x4*)dst)[j] = o;
}

// ---------------------------------------------------------------- GEMM main loop
template <int KDIM>
__device__ __forceinline__ void gemm_mainloop(
    const bf16_t* __restrict__ A, const bf16_t* __restrict__ Bt,
    bf16_t* As, bf16_t* Bs, int m0, int n0, int wave, int lane, f32x4 acc[4][4])
{
    const int quad = lane >> 4, l15 = lane & 15;
    const int wm = ((wave >> 1) << 6), wn = ((wave & 1) << 6);

    const int srow = (wave << 4) + (lane >> 2);                 // 0..63
    const int sw   = (((lane & 3) ^ ((srow >> 1) & 3)) << 3);   // swizzled elem offset
    const bf16_t* gA = A  + (size_t)(m0 + srow) * KDIM + sw;
    const bf16_t* gB = Bt + (size_t)(n0 + srow) * KDIM + sw;
    bf16_t* lA0 = As + wave * 512;
    bf16_t* lA1 = As + 2048 + wave * 512;
    bf16_t* lB0 = Bs + wave * 512;
    bf16_t* lB1 = Bs + 2048 + wave * 512;

    const int xorv = ((quad ^ ((l15 >> 1) & 3)) << 3);

    for (int k0 = 0; k0 < KDIM; k0 += 32) {
        __syncthreads();
        gload_lds16(gA + k0,                       lA0);
        gload_lds16(gA + (size_t)64 * KDIM + k0,   lA1);
        gload_lds16(gB + k0,                       lB0);
        gload_lds16(gB + (size_t)64 * KDIM + k0,   lB1);
        __syncthreads();

        bf16x8 af[4], bfr[4];
#pragma unroll
        for (int t = 0; t < 4; t++) {
            af[t]  = *(const bf16x8*)(As + (wm + t * 16 + l15) * 32 + xorv);
            bfr[t] = *(const bf16x8*)(Bs + (wn + t * 16 + l15) * 32 + xorv);
        }
#pragma unroll
        for (int mt = 0; mt < 4; mt++)
#pragma unroll
            for (int nt = 0; nt < 4; nt++)
                acc[mt][nt] = MFMA_BF16_K32(af[mt], bfr[nt], acc[mt][nt]);
    }
}

// ---------------------------------------------------------------- QKV projection
__global__ __launch_bounds__(256) void gemm_qkv(
    const bf16_t* __restrict__ A,   // [8192,768]
    const bf16_t* __restrict__ Bt,  // [2304,768]
    const float* __restrict__ bias, // [2304]
    bf16_t* __restrict__ qo, bf16_t* __restrict__ ko, f16_t* __restrict__ vo)
{
    __shared__ bf16_t As[128 * 32];
    __shared__ bf16_t Bs[128 * 32];
    const int tid = threadIdx.x, wave = tid >> 6, lane = tid & 63;
    const int quad = lane >> 4, l15 = lane & 15;
    const int m0 = blockIdx.y * 128, n0 = blockIdx.x * 128;
    f32x4 acc[4][4] = {};
    gemm_mainloop<768>(A, Bt, As, Bs, m0, n0, wave, lane, acc);

    const int wm = ((wave >> 1) << 6), wn = ((wave & 1) << 6);
#pragma unroll
    for (int nt = 0; nt < 4; nt++) {
        const int cc = n0 + wn + nt * 16 + l15;     // 0..2303
        const float bia = bias[cc];
        const int which = cc / 768;
        const int rem = cc - which * 768;
        const int h = rem >> 6, d = rem & 63;
        if (which < 2) {
            bf16_t* dst = (which == 0) ? qo : ko;
#pragma unroll
            for (int mt = 0; mt < 4; mt++) {
#pragma unroll
                for (int r = 0; r < 4; r++) {
                    const int row = m0 + wm + mt * 16 + quad * 4 + r; // 0..8191
                    const int b = row >> 12, t = row & 4095;
                    dst[((size_t)(b * 12 + h) * 4096 + t) * 64 + d] =
                        (bf16_t)(acc[mt][nt][r] + bia);
                }
            }
        } else {
            // V transposed f16: vo[((b*12+h)*64 + d)*4096 + t]
#pragma unroll
            for (int mt = 0; mt < 4; mt++) {
                const int row0 = m0 + wm + mt * 16 + quad * 4;
                const int b = row0 >> 12, t0 = row0 & 4095;
                f16x4 ov = { (f16_t)(acc[mt][nt][0] + bia),
                             (f16_t)(acc[mt][nt][1] + bia),
                             (f16_t)(acc[mt][nt][2] + bia),
                             (f16_t)(acc[mt][nt][3] + bia) };
                *(f16x4*)(vo + ((size_t)(b * 12 + h) * 64 + d) * 4096 + t0) = ov;
            }
        }
    }
}

// ---------------------------------------------------------------- output projection
__global__ __launch_bounds__(256) void gemm_proj(
    const bf16_t* __restrict__ A,   // y bf16 [8192,768]
    const bf16_t* __restrict__ Bt,  // W_proj bf16 [768,768]
    const float* __restrict__ bias, // [768]
    float* __restrict__ out)        // [8192,768] fp32
{
    __shared__ bf16_t As[128 * 32];
    __shared__ bf16_t Bs[128 * 32];
    const int tid = threadIdx.x, wave = tid >> 6, lane = tid & 63;
    const int quad = lane >> 4, l15 = lane & 15;
    const int m0 = blockIdx.y * 128, n0 = blockIdx.x * 128;
    f32x4 acc[4][4] = {};
    gemm_mainloop<768>(A, Bt, As, Bs, m0, n0, wave, lane, acc);

    const int wm = ((wave >> 1) << 6), wn = ((wave & 1) << 6);
#pragma unroll
    for (int nt = 0; nt < 4; nt++) {
        const int cc = n0 + wn + nt * 16 + l15;
        const float bia = bias[cc];
#pragma unroll
        for (int mt = 0; mt < 4; mt++) {
#pragma unroll
            for (int r = 0; r < 4; r++) {
                const int row = m0 + wm + mt * 16 + quad * 4 + r;
                out[(size_t)row * 768 + cc] = acc[mt][nt][r] + bia;
            }
        }
    }
}

// ---------------------------------------------------------------- flash attention v13
// v12 (K32 PV spanning a tile pair) + V LDS staging REMOVED. K and V rows are
// each consumed by exactly one wave exactly once per block, so LDS staging of
// V bought only coalescing; the per-XCD working set (3 bh x 1MB) fits the 4MB
// XCD L2 (that is what the xcd swizzle arranges), so PV's A-fragment is loaded
// global->reg directly: f16x4 at vtg[bh][dt*16+l15][kt*64 + w16 + quad*4],
// issued right after the barrier so ~200cy L2 latency hides under K ds_read +
// 16 QK MFMAs + softmax. LDS drops 64KB -> 36.8KB (K pair-dbuf + epilogue
// overlay) -> 4 blocks/CU; staging gload_lds volume and vmcnt drains halve;
// V's 8x ds_read_b64 per pair (and their bank conflicts) are deleted.
#define QSCALE 0.1803368801f   // log2(e)/8
__global__ __launch_bounds__(256, 3) void attn_fwd(
    const bf16_t* __restrict__ qg, const bf16_t* __restrict__ kg,
    const f16_t* __restrict__ vtg, bf16_t* __restrict__ y) // y [B,T,C] bf16
{
    __shared__ __align__(16) char smem[36864];
    bf16_t* Ks0 = (bf16_t*)(smem);              // 8KB each, [key][dim] swizzled
    bf16_t* Ks1 = (bf16_t*)(smem + 8192);
    bf16_t* Ks2 = (bf16_t*)(smem + 16384);
    bf16_t* Ks3 = (bf16_t*)(smem + 24576);
    float*  RedA = (float*)(smem);              // epilogue overlays (stride 68)
    float*  RedB = (float*)(smem + 17408);
    float*  Psr  = (float*)(smem + 34816);      // [4][64]
    float*  PsT  = (float*)(smem + 35840);      // [64]

    const int tid = threadIdx.x, wave = tid >> 6, lane = tid & 63;
    const int quad = lane >> 4, l15 = lane & 15;

    const int blk = blockIdx.x;            // 0..1535
    const int xcd = blk & 7;
    const int idx = blk >> 3;              // 0..191
    const int hl  = idx % 3;
    const int qt  = idx / 3;               // 0..63
    const int bh  = xcd * 3 + hl;          // 0..23
    const int b = bh / 12, h = bh - b * 12;
    const size_t base = (size_t)bh * 4096 * 64;

    // Q fragments for all 4 qrow-chunks (B-operand: n=l15, k=quad*8+j), *log2e/8
    bf16x8 qf[4][2];
#pragma unroll
    for (int qc = 0; qc < 4; qc++) {
        const int qrow = qt * 64 + qc * 16 + l15;
        qf[qc][0] = *(const bf16x8*)(qg + base + (size_t)qrow * 64 + quad * 8);
        qf[qc][1] = *(const bf16x8*)(qg + base + (size_t)qrow * 64 + 32 + quad * 8);
#pragma unroll
        for (int j = 0; j < 8; j++) {
            qf[qc][0][j] = (bf16_t)((float)qf[qc][0][j] * QSCALE);
            qf[qc][1][j] = (bf16_t)((float)qf[qc][1][j] * QSCALE);
        }
    }

    f32x4 O[4][4] = {};      // O^T partial: [dt][qc]; dim=dt*16+quad*4+r, qrow=qc*16+l15
    float psum[4] = {};      // per-lane partial row sums (qrow = qc*16+l15)
    const f16x2 one2 = { (f16_t)1.0f, (f16_t)1.0f };

    // K staging: 8 lanes per 128B row, 16B chunks XOR-swizzled on row&7
    const int srow8 = tid >> 3;                  // 0..31 (+32 for i=1)
    const int sc8   = (tid & 7) ^ (srow8 & 7);
    const int l8 = l15 & 7;
    const int w16 = wave << 4;
    const int ksoff = (quad ^ l8) << 3;          // K frag slot (elems)

    auto stage = [&](const bf16_t* kp_, bf16_t* Kd) {
#pragma unroll
        for (int i = 0; i < 2; i++)
            gload_lds16(kp_ + (i * 32 + srow8) * 64 + sc8 * 8, Kd + (i * 256 + tid) * 8);
    };

    // direct global->reg V fragments for a pair (tiles kt, kt+1):
    // vv[dt][t] = V^T[dim=dt*16+l15][key = (kt+t)*64 + w16 + quad*4 .. +3]
    auto vload = [&](const f16_t* vb_, f16x4 vv[4][2]) {
#pragma unroll
        for (int dt = 0; dt < 4; dt++) {
            vv[dt][0] = *(const f16x4*)(vb_ + (size_t)dt * 65536);
            vv[dt][1] = *(const f16x4*)(vb_ + (size_t)dt * 65536 + 64);
        }
    };

    // joint compute over a pair of 64-key tiles (A,B): QK^T+softmax per tile,
    // then one K=32 PV spanning both tiles' keys (V already in registers).
    auto compute_pair = [&](const bf16_t* ksA, const bf16_t* ksB, const f16x4 vv[4][2]) {
        // ---- S^T tile A then tile B (wave's 16 keys x 64 qrows each)
        const bf16_t* krA = ksA + (w16 + l15) * 64;
        const bf16_t* krB = ksB + (w16 + l15) * 64;
        bf16x8 kfA0 = *(const bf16x8*)(krA + ksoff);
        bf16x8 kfA1 = *(const bf16x8*)(krA + (ksoff ^ 32));
        bf16x8 kfB0 = *(const bf16x8*)(krB + ksoff);
        bf16x8 kfB1 = *(const bf16x8*)(krB + (ksoff ^ 32));
        f32x4 scA[4], scB[4];
        __builtin_amdgcn_s_setprio(1);
#pragma unroll
        for (int qc = 0; qc < 4; qc++) {
            f32x4 s = {};
            s = MFMA_BF16_K32(kfA0, qf[qc][0], s);
            s = MFMA_BF16_K32(kfA1, qf[qc][1], s);
            scA[qc] = s;
        }
#pragma unroll
        for (int qc = 0; qc < 4; qc++) {
            f32x4 s = {};
            s = MFMA_BF16_K32(kfB0, qf[qc][0], s);
            s = MFMA_BF16_K32(kfB1, qf[qc][1], s);
            scB[qc] = s;
        }
        __builtin_amdgcn_s_setprio(0);
        // ---- P = exp2(S^T) for both tiles -> packed f16x8 B-operand + row sums
        f16x8 pf8[4];
#pragma unroll
        for (int qc = 0; qc < 4; qc++) {
            float a0 = __builtin_amdgcn_exp2f(scA[qc][0]);
            float a1 = __builtin_amdgcn_exp2f(scA[qc][1]);
            float a2 = __builtin_amdgcn_exp2f(scA[qc][2]);
            float a3 = __builtin_amdgcn_exp2f(scA[qc][3]);
            float b0 = __builtin_amdgcn_exp2f(scB[qc][0]);
            float b1 = __builtin_amdgcn_exp2f(scB[qc][1]);
            float b2 = __builtin_amdgcn_exp2f(scB[qc][2]);
            float b3 = __builtin_amdgcn_exp2f(scB[qc][3]);
            f16x2 loA = pkrtz(a0, a1);
            f16x2 hiA = pkrtz(a2, a3);
            f16x2 loB = pkrtz(b0, b1);
            f16x2 hiB = pkrtz(b2, b3);
            psum[qc] = __builtin_amdgcn_fdot2(loA, one2, psum[qc], false);
            psum[qc] = __builtin_amdgcn_fdot2(hiA, one2, psum[qc], false);
            psum[qc] = __builtin_amdgcn_fdot2(loB, one2, psum[qc], false);
            psum[qc] = __builtin_amdgcn_fdot2(hiB, one2, psum[qc], false);
            union { f16x8 v; f16x2 h[4]; } u;
            u.h[0] = loA; u.h[1] = hiA; u.h[2] = loB; u.h[3] = hiB;
            pf8[qc] = u.v;
        }
        // ---- O^T += V^T P with K=32 spanning both tiles: V from registers
        __builtin_amdgcn_s_setprio(1);
#pragma unroll
        for (int dt = 0; dt < 4; dt++) {
            union { f16x8 v; f16x4 h[2]; } uv;
            uv.h[0] = vv[dt][0]; uv.h[1] = vv[dt][1];
#pragma unroll
            for (int qc = 0; qc < 4; qc++)
                O[dt][qc] = MFMA_F16_K32(uv.v, pf8[qc], O[dt][qc]);
        }
        __builtin_amdgcn_s_setprio(0);
    };

    const bf16_t* kp = kg + base;    // +4096 elems (8KB) per 64-key tile
    const f16_t*  vb = vtg + base + (size_t)l15 * 4096 + w16 + quad * 4;
    stage(kp, Ks0); stage(kp + 4096, Ks1); kp += 8192;   // pair 0
    f16x4 v0[4][2], v1[4][2];
    for (int p = 0; p < 32; p += 2) {
        __syncthreads();                 // pair p K staged; prev Ks2/3 readers done
        vload(vb, v0);                   // V for pair p (direct, hides under QK+softmax)
        stage(kp, Ks2); stage(kp + 4096, Ks3); kp += 8192;   // K pair p+1
        compute_pair(Ks0, Ks1, v0);
        __syncthreads();
        vload(vb + 128, v1);             // V for pair p+1
        if (p + 2 < 32) { stage(kp, Ks0); stage(kp + 4096, Ks1); kp += 8192; }
        compute_pair(Ks2, Ks3, v1);
        vb += 256;
    }

    // ================= epilogue: reduce O & psum across the 4 key-split waves
#pragma unroll
    for (int qc = 0; qc < 4; qc++) {
        psum[qc] += __shfl_xor(psum[qc], 16, 64);
        psum[qc] += __shfl_xor(psum[qc], 32, 64);
    }
    __syncthreads();   // K-loop LDS quiesced; overlay safe
    if (wave == 2) {
#pragma unroll
        for (int dt = 0; dt < 4; dt++)
#pragma unroll
            for (int qc = 0; qc < 4; qc++)
                *(f32x4*)(RedA + (qc * 16 + l15) * 68 + dt * 16 + quad * 4) = O[dt][qc];
    } else if (wave == 3) {
#pragma unroll
        for (int dt = 0; dt < 4; dt++)
#pragma unroll
            for (int qc = 0; qc < 4; qc++)
                *(f32x4*)(RedB + (qc * 16 + l15) * 68 + dt * 16 + quad * 4) = O[dt][qc];
    }
    if (quad == 0) {
#pragma unroll
        for (int qc = 0; qc < 4; qc++) Psr[wave * 64 + qc * 16 + l15] = psum[qc];
    }
    __syncthreads();   // S2
    if (wave == 0) {
#pragma unroll
        for (int dt = 0; dt < 4; dt++)
#pragma unroll
            for (int qc = 0; qc < 4; qc++)
                O[dt][qc] += *(const f32x4*)(RedA + (qc * 16 + l15) * 68 + dt * 16 + quad * 4);
    } else if (wave == 1) {
#pragma unroll
        for (int dt = 0; dt < 4; dt++)
#pragma unroll
            for (int qc = 0; qc < 4; qc++)
                O[dt][qc] += *(const f32x4*)(RedB + (qc * 16 + l15) * 68 + dt * 16 + quad * 4);
    }
    __syncthreads();   // S3
    if (wave == 1) {
#pragma unroll
        for (int dt = 0; dt < 4; dt++)
#pragma unroll
            for (int qc = 0; qc < 4; qc++)
                *(f32x4*)(RedA + (qc * 16 + l15) * 68 + dt * 16 + quad * 4) = O[dt][qc];
    } else if (wave == 3) {
        PsT[lane] = Psr[lane] + Psr[64 + lane] + Psr[128 + lane] + Psr[192 + lane];
    }
    __syncthreads();   // S4
    if (wave == 0) {
#pragma unroll
        for (int qc = 0; qc < 4; qc++) {
            const float rcp = 1.0f / PsT[qc * 16 + l15];
            const int t = qt * 64 + qc * 16 + l15;
            bf16_t* yr = y + ((size_t)b * 4096 + t) * 768 + h * 64 + quad * 4;
#pragma unroll
            for (int dt = 0; dt < 4; dt++) {
                f32x4 o4 = O[dt][qc] +
                    *(const f32x4*)(RedA + (qc * 16 + l15) * 68 + dt * 16 + quad * 4);
                bf16x4 ov = { (bf16_t)(o4[0] * rcp), (bf16_t)(o4[1] * rcp),
                              (bf16_t)(o4[2] * rcp), (bf16_t)(o4[3] * rcp) };
                *(bf16x4*)(yr + dt * 16) = ov;
            }
        }
    }
}

// ---------------------------------------------------------------- launch
extern "C" void kernel_launch(void* const* d_in, const int* in_sizes, int n_in,
                              void* d_out, int out_size, void* d_ws, size_t ws_size,
                              hipStream_t stream) {
    const float* x  = (const float*)d_in[0]; // [2,4096,768]
    const float* Wa = (const float*)d_in[1]; // [2304,768]
    const float* ba = (const float*)d_in[2]; // [2304]
    const float* Wp = (const float*)d_in[3]; // [768,768]
    const float* bp = (const float*)d_in[4]; // [768]
    float* out = (float*)d_out;              // [2,4096,768]

    char* ws = (char*)d_ws;
    bf16_t* xb  = (bf16_t*)(ws);                 //  6291456 elts
    bf16_t* Wab = (bf16_t*)(ws + 12582912);      //  1769472
    bf16_t* Wpb = (bf16_t*)(ws + 16121856);      //   589824
    bf16_t* qb  = (bf16_t*)(ws + 17301504);      //  [B,H,T,D] bf16
    bf16_t* kb  = (bf16_t*)(ws + 29884416);      //  [B,H,T,D] bf16
    f16_t*  vtb = (f16_t*)(ws + 42467328);       //  [B,H,D,T] f16 (transposed)
    bf16_t* yb  = (bf16_t*)(ws + 55050240);      //  [B,T,C] bf16

    cvt_all<<<8448, 256, 0, stream>>>(x, Wa, Wp, xb, Wab, Wpb);
    gemm_qkv <<<dim3(18, 64), 256, 0, stream>>>(xb, Wab, ba, qb, kb, vtb);
    attn_fwd <<<1536, 256, 0, stream>>>(qb, kb, vtb, yb);
    gemm_proj<<<dim3( 6, 64), 256, 0, stream>>>(yb, Wpb, bp, out);
}

// Round 3
// 431.796 us; speedup vs baseline: 1.0991x; 1.0991x over previous
//
#include <hip/hip_runtime.h>
#include <stdint.h>
#include <stddef.h>

typedef __bf16 bf16_t;
typedef bf16_t bf16x4 __attribute__((ext_vector_type(4)));
typedef bf16_t bf16x8 __attribute__((ext_vector_type(8)));
typedef float  f32x4  __attribute__((ext_vector_type(4)));
typedef _Float16 f16_t;
typedef f16_t f16x2 __attribute__((ext_vector_type(2)));
typedef f16_t f16x4 __attribute__((ext_vector_type(4)));
typedef f16_t f16x8 __attribute__((ext_vector_type(8)));
typedef __fp16 fp16x2_raw __attribute__((ext_vector_type(2)));   // cvt_pkrtz native type

__device__ __forceinline__ f16x2 pkrtz(float a, float b) {
    fp16x2_raw r = __builtin_amdgcn_cvt_pkrtz(a, b);
    union { fp16x2_raw r; f16x2 h; } u;
    u.r = r;
    return u.h;
}

#define MFMA_BF16_K32(a, b, c) __builtin_amdgcn_mfma_f32_16x16x32_bf16(a, b, c, 0, 0, 0)
#define MFMA_F16_K32(a, b, c)  __builtin_amdgcn_mfma_f32_16x16x32_f16(a, b, c, 0, 0, 0)

// ---------------------------------------------------------------- helpers
__device__ __forceinline__ void gload_lds16(const void* g, void* l) {
    __builtin_amdgcn_global_load_lds(
        (const __attribute__((address_space(1))) void*)g,
        (__attribute__((address_space(3))) void*)l,
        16, 0, 0);
}

// ---------------------------------------------------------------- fused fp32 -> bf16 casts
#define NX 1572864           // x  float4 count
#define NWA 442368           // Wa float4 count
#define NWP 147456           // Wp float4 count
__global__ void cvt_all(const float* __restrict__ x, const float* __restrict__ Wa,
                        const float* __restrict__ Wp, bf16_t* __restrict__ xb,
                        bf16_t* __restrict__ Wab, bf16_t* __restrict__ Wpb) {
    int i = blockIdx.x * blockDim.x + threadIdx.x;
    const float4* src; bf16_t* dst; int j;
    if (i < NX)            { src = (const float4*)x;  dst = xb;  j = i; }
    else if (i < NX + NWA) { src = (const float4*)Wa; dst = Wab; j = i - NX; }
    else                   { src = (const float4*)Wp; dst = Wpb; j = i - NX - NWA; }
    float4 f = src[j];
    bf16x4 o = { (bf16_t)f.x, (bf16_t)f.y, (bf16_t)f.z, (bf16_t)f.w };
    ((bf16x4*)dst)[j] = o;
}

// ---------------------------------------------------------------- GEMM main loop
template <int KDIM>
__device__ __forceinline__ void gemm_mainloop(
    const bf16_t* __restrict__ A, const bf16_t* __restrict__ Bt,
    bf16_t* As, bf16_t* Bs, int m0, int n0, int wave, int lane, f32x4 acc[4][4])
{
    const int quad = lane >> 4, l15 = lane & 15;
    const int wm = ((wave >> 1) << 6), wn = ((wave & 1) << 6);

    const int srow = (wave << 4) + (lane >> 2);                 // 0..63
    const int sw   = (((lane & 3) ^ ((srow >> 1) & 3)) << 3);   // swizzled elem offset
    const bf16_t* gA = A  + (size_t)(m0 + srow) * KDIM + sw;
    const bf16_t* gB = Bt + (size_t)(n0 + srow) * KDIM + sw;
    bf16_t* lA0 = As + wave * 512;
    bf16_t* lA1 = As + 2048 + wave * 512;
    bf16_t* lB0 = Bs + wave * 512;
    bf16_t* lB1 = Bs + 2048 + wave * 512;

    const int xorv = ((quad ^ ((l15 >> 1) & 3)) << 3);

    for (int k0 = 0; k0 < KDIM; k0 += 32) {
        __syncthreads();
        gload_lds16(gA + k0,                       lA0);
        gload_lds16(gA + (size_t)64 * KDIM + k0,   lA1);
        gload_lds16(gB + k0,                       lB0);
        gload_lds16(gB + (size_t)64 * KDIM + k0,   lB1);
        __syncthreads();

        bf16x8 af[4], bfr[4];
#pragma unroll
        for (int t = 0; t < 4; t++) {
            af[t]  = *(const bf16x8*)(As + (wm + t * 16 + l15) * 32 + xorv);
            bfr[t] = *(const bf16x8*)(Bs + (wn + t * 16 + l15) * 32 + xorv);
        }
#pragma unroll
        for (int mt = 0; mt < 4; mt++)
#pragma unroll
            for (int nt = 0; nt < 4; nt++)
                acc[mt][nt] = MFMA_BF16_K32(af[mt], bfr[nt], acc[mt][nt]);
    }
}

// ---------------------------------------------------------------- QKV projection
__global__ __launch_bounds__(256) void gemm_qkv(
    const bf16_t* __restrict__ A,   // [8192,768]
    const bf16_t* __restrict__ Bt,  // [2304,768]
    const float* __restrict__ bias, // [2304]
    bf16_t* __restrict__ qo, bf16_t* __restrict__ ko, f16_t* __restrict__ vo)
{
    __shared__ bf16_t As[128 * 32];
    __shared__ bf16_t Bs[128 * 32];
    const int tid = threadIdx.x, wave = tid >> 6, lane = tid & 63;
    const int quad = lane >> 4, l15 = lane & 15;
    const int m0 = blockIdx.y * 128, n0 = blockIdx.x * 128;
    f32x4 acc[4][4] = {};
    gemm_mainloop<768>(A, Bt, As, Bs, m0, n0, wave, lane, acc);

    const int wm = ((wave >> 1) << 6), wn = ((wave & 1) << 6);
#pragma unroll
    for (int nt = 0; nt < 4; nt++) {
        const int cc = n0 + wn + nt * 16 + l15;     // 0..2303
        const float bia = bias[cc];
        const int which = cc / 768;
        const int rem = cc - which * 768;
        const int h = rem >> 6, d = rem & 63;
        if (which < 2) {
            bf16_t* dst = (which == 0) ? qo : ko;
#pragma unroll
            for (int mt = 0; mt < 4; mt++) {
#pragma unroll
                for (int r = 0; r < 4; r++) {
                    const int row = m0 + wm + mt * 16 + quad * 4 + r; // 0..8191
                    const int b = row >> 12, t = row & 4095;
                    dst[((size_t)(b * 12 + h) * 4096 + t) * 64 + d] =
                        (bf16_t)(acc[mt][nt][r] + bia);
                }
            }
        } else {
            // V transposed f16: vo[((b*12+h)*64 + d)*4096 + t]
#pragma unroll
            for (int mt = 0; mt < 4; mt++) {
                const int row0 = m0 + wm + mt * 16 + quad * 4;
                const int b = row0 >> 12, t0 = row0 & 4095;
                f16x4 ov = { (f16_t)(acc[mt][nt][0] + bia),
                             (f16_t)(acc[mt][nt][1] + bia),
                             (f16_t)(acc[mt][nt][2] + bia),
                             (f16_t)(acc[mt][nt][3] + bia) };
                *(f16x4*)(vo + ((size_t)(b * 12 + h) * 64 + d) * 4096 + t0) = ov;
            }
        }
    }
}

// ---------------------------------------------------------------- output projection
__global__ __launch_bounds__(256) void gemm_proj(
    const bf16_t* __restrict__ A,   // y bf16 [8192,768]
    const bf16_t* __restrict__ Bt,  // W_proj bf16 [768,768]
    const float* __restrict__ bias, // [768]
    float* __restrict__ out)        // [8192,768] fp32
{
    __shared__ bf16_t As[128 * 32];
    __shared__ bf16_t Bs[128 * 32];
    const int tid = threadIdx.x, wave = tid >> 6, lane = tid & 63;
    const int quad = lane >> 4, l15 = lane & 15;
    const int m0 = blockIdx.y * 128, n0 = blockIdx.x * 128;
    f32x4 acc[4][4] = {};
    gemm_mainloop<768>(A, Bt, As, Bs, m0, n0, wave, lane, acc);

    const int wm = ((wave >> 1) << 6), wn = ((wave & 1) << 6);
#pragma unroll
    for (int nt = 0; nt < 4; nt++) {
        const int cc = n0 + wn + nt * 16 + l15;
        const float bia = bias[cc];
#pragma unroll
        for (int mt = 0; mt < 4; mt++) {
#pragma unroll
            for (int r = 0; r < 4; r++) {
                const int row = m0 + wm + mt * 16 + quad * 4 + r;
                out[(size_t)row * 768 + cc] = acc[mt][nt][r] + bia;
            }
        }
    }
}

// ---------------------------------------------------------------- flash attention v14
// v12 base (K32 PV spanning a tile pair, V LDS-staged) with K moved from LDS
// to REGISTERS. Per wave the K fragment set is a contiguous 2KB block (16
// consecutive 128B key rows): two dwordx4 loads per lane, dense 64B segments,
// the exact same global addresses the K gload_lds staging issued (round-1
// FETCH=23MB proves they are L2-served across the 64 q-blocks per bh). V's
// fragments are scattered 32B@8KB-stride (round-2: 4x HBM over-fetch) so V
// stays gload_lds-staged + swizzled. LDS 64KB -> 36.8KB (4 blocks/CU); K-pair
// regs double-buffered (+32 VGPR, ~116 total, under the 128 cliff); half the
// gload_lds + vmcnt drain per barrier; K's ds_read_b128s deleted.
#define QSCALE 0.1803368801f   // log2(e)/8
__global__ __launch_bounds__(256, 3) void attn_fwd(
    const bf16_t* __restrict__ qg, const bf16_t* __restrict__ kg,
    const f16_t* __restrict__ vtg, bf16_t* __restrict__ y) // y [B,T,C] bf16
{
    __shared__ __align__(16) char smem[36864];
    f16_t*  Vt0 = (f16_t*)(smem);               // 8KB each, [dim][key] swizzled
    f16_t*  Vt1 = (f16_t*)(smem + 8192);
    f16_t*  Vt2 = (f16_t*)(smem + 16384);
    f16_t*  Vt3 = (f16_t*)(smem + 24576);
    float*  RedA = (float*)(smem);              // epilogue overlays (stride 68)
    float*  RedB = (float*)(smem + 17408);
    float*  Psr  = (float*)(smem + 34816);      // [4][64]
    float*  PsT  = (float*)(smem + 35840);      // [64]

    const int tid = threadIdx.x, wave = tid >> 6, lane = tid & 63;
    const int quad = lane >> 4, l15 = lane & 15;

    const int blk = blockIdx.x;            // 0..1535
    const int xcd = blk & 7;
    const int idx = blk >> 3;              // 0..191
    const int hl  = idx % 3;
    const int qt  = idx / 3;               // 0..63
    const int bh  = xcd * 3 + hl;          // 0..23
    const int b = bh / 12, h = bh - b * 12;
    const size_t base = (size_t)bh * 4096 * 64;

    // Q fragments for all 4 qrow-chunks (B-operand: n=l15, k=quad*8+j), *log2e/8
    bf16x8 qf[4][2];
#pragma unroll
    for (int qc = 0; qc < 4; qc++) {
        const int qrow = qt * 64 + qc * 16 + l15;
        qf[qc][0] = *(const bf16x8*)(qg + base + (size_t)qrow * 64 + quad * 8);
        qf[qc][1] = *(const bf16x8*)(qg + base + (size_t)qrow * 64 + 32 + quad * 8);
#pragma unroll
        for (int j = 0; j < 8; j++) {
            qf[qc][0][j] = (bf16_t)((float)qf[qc][0][j] * QSCALE);
            qf[qc][1][j] = (bf16_t)((float)qf[qc][1][j] * QSCALE);
        }
    }

    f32x4 O[4][4] = {};      // O^T partial: [dt][qc]; dim=dt*16+quad*4+r, qrow=qc*16+l15
    float psum[4] = {};      // per-lane partial row sums (qrow = qc*16+l15)
    const f16x2 one2 = { (f16_t)1.0f, (f16_t)1.0f };

    // V staging: 8 lanes per 128B row, 16B chunks XOR-swizzled on row&7
    const int srow8 = tid >> 3;                  // 0..31 (+32 for i=1)
    const int sc8   = (tid & 7) ^ (srow8 & 7);
    const int l8 = l15 & 7;
    const int w16 = wave << 4;
    const int vslot = ((wave << 1) | (quad >> 1)) ^ l8;          // V frag 16B slot
    const int q0off = (quad & 1) * 8;

    auto stage = [&](const f16_t* vp_, f16_t* Vd) {
#pragma unroll
        for (int i = 0; i < 2; i++)
            gload_lds16(vp_ + (size_t)(i * 32 + srow8) * 4096 + sc8 * 8, Vd + (i * 256 + tid) * 8);
    };

    // K direct global->reg for a pair of tiles (t, t+1):
    // kr[0..1] = K[key=t*64+w16+l15][quad*8.. , 32+quad*8..], kr[2..3] same tile t+1
    const bf16_t* kpg = kg + base + (size_t)(w16 + l15) * 64 + quad * 8;
    auto kload = [&](int t, bf16x8 kr[4]) {
        const bf16_t* p0 = kpg + (size_t)t * 4096;
        kr[0] = *(const bf16x8*)(p0);
        kr[1] = *(const bf16x8*)(p0 + 32);
        kr[2] = *(const bf16x8*)(p0 + 4096);
        kr[3] = *(const bf16x8*)(p0 + 4096 + 32);
    };

    // joint compute over a pair of 64-key tiles (A,B): QK^T+softmax per tile,
    // then one K=32 PV spanning both tiles' keys (K in regs, V from LDS).
    auto compute_pair = [&](const bf16x8 kr[4], const f16_t* vsA, const f16_t* vsB) {
        f32x4 scA[4], scB[4];
        __builtin_amdgcn_s_setprio(1);
#pragma unroll
        for (int qc = 0; qc < 4; qc++) {
            f32x4 s = {};
            s = MFMA_BF16_K32(kr[0], qf[qc][0], s);
            s = MFMA_BF16_K32(kr[1], qf[qc][1], s);
            scA[qc] = s;
        }
#pragma unroll
        for (int qc = 0; qc < 4; qc++) {
            f32x4 s = {};
            s = MFMA_BF16_K32(kr[2], qf[qc][0], s);
            s = MFMA_BF16_K32(kr[3], qf[qc][1], s);
            scB[qc] = s;
        }
        __builtin_amdgcn_s_setprio(0);
        // ---- P = exp2(S^T) for both tiles -> packed f16x8 B-operand + row sums
        f16x8 pf8[4];
#pragma unroll
        for (int qc = 0; qc < 4; qc++) {
            float a0 = __builtin_amdgcn_exp2f(scA[qc][0]);
            float a1 = __builtin_amdgcn_exp2f(scA[qc][1]);
            float a2 = __builtin_amdgcn_exp2f(scA[qc][2]);
            float a3 = __builtin_amdgcn_exp2f(scA[qc][3]);
            float b0 = __builtin_amdgcn_exp2f(scB[qc][0]);
            float b1 = __builtin_amdgcn_exp2f(scB[qc][1]);
            float b2 = __builtin_amdgcn_exp2f(scB[qc][2]);
            float b3 = __builtin_amdgcn_exp2f(scB[qc][3]);
            f16x2 loA = pkrtz(a0, a1);
            f16x2 hiA = pkrtz(a2, a3);
            f16x2 loB = pkrtz(b0, b1);
            f16x2 hiB = pkrtz(b2, b3);
            psum[qc] = __builtin_amdgcn_fdot2(loA, one2, psum[qc], false);
            psum[qc] = __builtin_amdgcn_fdot2(hiA, one2, psum[qc], false);
            psum[qc] = __builtin_amdgcn_fdot2(loB, one2, psum[qc], false);
            psum[qc] = __builtin_amdgcn_fdot2(hiB, one2, psum[qc], false);
            union { f16x8 v; f16x2 h[4]; } u;
            u.h[0] = loA; u.h[1] = hiA; u.h[2] = loB; u.h[3] = hiB;
            pf8[qc] = u.v;
        }
        // ---- O^T += V^T P with K=32 spanning both tiles: V from LDS
        __builtin_amdgcn_s_setprio(1);
#pragma unroll
        for (int dt = 0; dt < 4; dt++) {
            const char* vrA = (const char*)(vsA + (dt * 16 + l15) * 64);
            const char* vrB = (const char*)(vsB + (dt * 16 + l15) * 64);
            f16x4 vA = *(const f16x4*)(vrA + vslot * 16 + q0off);
            f16x4 vB = *(const f16x4*)(vrB + vslot * 16 + q0off);
            union { f16x8 v; f16x4 h[2]; } uv;
            uv.h[0] = vA; uv.h[1] = vB;
#pragma unroll
            for (int qc = 0; qc < 4; qc++)
                O[dt][qc] = MFMA_F16_K32(uv.v, pf8[qc], O[dt][qc]);
        }
        __builtin_amdgcn_s_setprio(0);
    };

    const f16_t* vp = vtg + base;    // +64 elems per 64-key tile
    bf16x8 kA[4], kB[4];
    kload(0, kA);
    stage(vp, Vt0); stage(vp + 64, Vt1);
    for (int t = 0; t < 64; t += 4) {
        __syncthreads();                 // V tiles t,t+1 staged; Vt2/3 readers done
        kload(t + 2, kB);
        stage(vp + 128, Vt2); stage(vp + 192, Vt3);
        compute_pair(kA, Vt0, Vt1);
        __syncthreads();                 // V tiles t+2,t+3 staged; Vt0/1 readers done
        if (t + 4 < 64) {
            kload(t + 4, kA);
            stage(vp + 256, Vt0); stage(vp + 320, Vt1);
        }
        compute_pair(kB, Vt2, Vt3);
        vp += 256;
    }

    // ================= epilogue: reduce O & psum across the 4 key-split waves
#pragma unroll
    for (int qc = 0; qc < 4; qc++) {
        psum[qc] += __shfl_xor(psum[qc], 16, 64);
        psum[qc] += __shfl_xor(psum[qc], 32, 64);
    }
    __syncthreads();   // K-loop LDS quiesced; overlay safe
    if (wave == 2) {
#pragma unroll
        for (int dt = 0; dt < 4; dt++)
#pragma unroll
            for (int qc = 0; qc < 4; qc++)
                *(f32x4*)(RedA + (qc * 16 + l15) * 68 + dt * 16 + quad * 4) = O[dt][qc];
    } else if (wave == 3) {
#pragma unroll
        for (int dt = 0; dt < 4; dt++)
#pragma unroll
            for (int qc = 0; qc < 4; qc++)
                *(f32x4*)(RedB + (qc * 16 + l15) * 68 + dt * 16 + quad * 4) = O[dt][qc];
    }
    if (quad == 0) {
#pragma unroll
        for (int qc = 0; qc < 4; qc++) Psr[wave * 64 + qc * 16 + l15] = psum[qc];
    }
    __syncthreads();   // S2
    if (wave == 0) {
#pragma unroll
        for (int dt = 0; dt < 4; dt++)
#pragma unroll
            for (int qc = 0; qc < 4; qc++)
                O[dt][qc] += *(const f32x4*)(RedA + (qc * 16 + l15) * 68 + dt * 16 + quad * 4);
    } else if (wave == 1) {
#pragma unroll
        for (int dt = 0; dt < 4; dt++)
#pragma unroll
            for (int qc = 0; qc < 4; qc++)
                O[dt][qc] += *(const f32x4*)(RedB + (qc * 16 + l15) * 68 + dt * 16 + quad * 4);
    }
    __syncthreads();   // S3
    if (wave == 1) {
#pragma unroll
        for (int dt = 0; dt < 4; dt++)
#pragma unroll
            for (int qc = 0; qc < 4; qc++)
                *(f32x4*)(RedA + (qc * 16 + l15) * 68 + dt * 16 + quad * 4) = O[dt][qc];
    } else if (wave == 3) {
        PsT[lane] = Psr[lane] + Psr[64 + lane] + Psr[128 + lane] + Psr[192 + lane];
    }
    __syncthreads();   // S4
    if (wave == 0) {
#pragma unroll
        for (int qc = 0; qc < 4; qc++) {
            const float rcp = 1.0f / PsT[qc * 16 + l15];
            const int t = qt * 64 + qc * 16 + l15;
            bf16_t* yr = y + ((size_t)b * 4096 + t) * 768 + h * 64 + quad * 4;
#pragma unroll
            for (int dt = 0; dt < 4; dt++) {
                f32x4 o4 = O[dt][qc] +
                    *(const f32x4*)(RedA + (qc * 16 + l15) * 68 + dt * 16 + quad * 4);
                bf16x4 ov = { (bf16_t)(o4[0] * rcp), (bf16_t)(o4[1] * rcp),
                              (bf16_t)(o4[2] * rcp), (bf16_t)(o4[3] * rcp) };
                *(bf16x4*)(yr + dt * 16) = ov;
            }
        }
    }
}

// ---------------------------------------------------------------- launch
extern "C" void kernel_launch(void* const* d_in, const int* in_sizes, int n_in,
                              void* d_out, int out_size, void* d_ws, size_t ws_size,
                              hipStream_t stream) {
    const float* x  = (const float*)d_in[0]; // [2,4096,768]
    const float* Wa = (const float*)d_in[1]; // [2304,768]
    const float* ba = (const float*)d_in[2]; // [2304]
    const float* Wp = (const float*)d_in[3]; // [768,768]
    const float* bp = (const float*)d_in[4]; // [768]
    float* out = (float*)d_out;              // [2,4096,768]

    char* ws = (char*)d_ws;
    bf16_t* xb  = (bf16_t*)(ws);                 //  6291456 elts
    bf16_t* Wab = (bf16_t*)(ws + 12582912);      //  1769472
    bf16_t* Wpb = (bf16_t*)(ws + 16121856);      //   589824
    bf16_t* qb  = (bf16_t*)(ws + 17301504);      //  [B,H,T,D] bf16
    bf16_t* kb  = (bf16_t*)(ws + 29884416);      //  [B,H,T,D] bf16
    f16_t*  vtb = (f16_t*)(ws + 42467328);       //  [B,H,D,T] f16 (transposed)
    bf16_t* yb  = (bf16_t*)(ws + 55050240);      //  [B,T,C] bf16

    cvt_all<<<8448, 256, 0, stream>>>(x, Wa, Wp, xb, Wab, Wpb);
    gemm_qkv <<<dim3(18, 64), 256, 0, stream>>>(xb, Wab, ba, qb, kb, vtb);
    attn_fwd <<<1536, 256, 0, stream>>>(qb, kb, vtb, yb);
    gemm_proj<<<dim3( 6, 64), 256, 0, stream>>>(yb, Wpb, bp, out);
}

// Round 4
// 431.101 us; speedup vs baseline: 1.1008x; 1.0016x over previous
//
#include <hip/hip_runtime.h>
#include <stdint.h>
#include <stddef.h>

typedef __bf16 bf16_t;
typedef bf16_t bf16x4 __attribute__((ext_vector_type(4)));
typedef bf16_t bf16x8 __attribute__((ext_vector_type(8)));
typedef float  f32x4  __attribute__((ext_vector_type(4)));
typedef _Float16 f16_t;
typedef f16_t f16x2 __attribute__((ext_vector_type(2)));
typedef f16_t f16x4 __attribute__((ext_vector_type(4)));
typedef f16_t f16x8 __attribute__((ext_vector_type(8)));
typedef __fp16 fp16x2_raw __attribute__((ext_vector_type(2)));   // cvt_pkrtz native type

__device__ __forceinline__ f16x2 pkrtz(float a, float b) {
    fp16x2_raw r = __builtin_amdgcn_cvt_pkrtz(a, b);
    union { fp16x2_raw r; f16x2 h; } u;
    u.r = r;
    return u.h;
}

#define MFMA_BF16_K32(a, b, c) __builtin_amdgcn_mfma_f32_16x16x32_bf16(a, b, c, 0, 0, 0)
#define MFMA_F16_K32(a, b, c)  __builtin_amdgcn_mfma_f32_16x16x32_f16(a, b, c, 0, 0, 0)

// ---------------------------------------------------------------- helpers
__device__ __forceinline__ void gload_lds16(const void* g, void* l) {
    __builtin_amdgcn_global_load_lds(
        (const __attribute__((address_space(1))) void*)g,
        (__attribute__((address_space(3))) void*)l,
        16, 0, 0);
}

// ---------------------------------------------------------------- fused fp32 -> bf16 casts
#define NX 1572864           // x  float4 count
#define NWA 442368           // Wa float4 count
#define NWP 147456           // Wp float4 count
__global__ void cvt_all(const float* __restrict__ x, const float* __restrict__ Wa,
                        const float* __restrict__ Wp, bf16_t* __restrict__ xb,
                        bf16_t* __restrict__ Wab, bf16_t* __restrict__ Wpb) {
    int i = blockIdx.x * blockDim.x + threadIdx.x;
    const float4* src; bf16_t* dst; int j;
    if (i < NX)            { src = (const float4*)x;  dst = xb;  j = i; }
    else if (i < NX + NWA) { src = (const float4*)Wa; dst = Wab; j = i - NX; }
    else                   { src = (const float4*)Wp; dst = Wpb; j = i - NX - NWA; }
    float4 f = src[j];
    bf16x4 o = { (bf16_t)f.x, (bf16_t)f.y, (bf16_t)f.z, (bf16_t)f.w };
    ((bf16x4*)dst)[j] = o;
}

// ---------------------------------------------------------------- GEMM main loop
template <int KDIM>
__device__ __forceinline__ void gemm_mainloop(
    const bf16_t* __restrict__ A, const bf16_t* __restrict__ Bt,
    bf16_t* As, bf16_t* Bs, int m0, int n0, int wave, int lane, f32x4 acc[4][4])
{
    const int quad = lane >> 4, l15 = lane & 15;
    const int wm = ((wave >> 1) << 6), wn = ((wave & 1) << 6);

    const int srow = (wave << 4) + (lane >> 2);                 // 0..63
    const int sw   = (((lane & 3) ^ ((srow >> 1) & 3)) << 3);   // swizzled elem offset
    const bf16_t* gA = A  + (size_t)(m0 + srow) * KDIM + sw;
    const bf16_t* gB = Bt + (size_t)(n0 + srow) * KDIM + sw;
    bf16_t* lA0 = As + wave * 512;
    bf16_t* lA1 = As + 2048 + wave * 512;
    bf16_t* lB0 = Bs + wave * 512;
    bf16_t* lB1 = Bs + 2048 + wave * 512;

    const int xorv = ((quad ^ ((l15 >> 1) & 3)) << 3);

    for (int k0 = 0; k0 < KDIM; k0 += 32) {
        __syncthreads();
        gload_lds16(gA + k0,                       lA0);
        gload_lds16(gA + (size_t)64 * KDIM + k0,   lA1);
        gload_lds16(gB + k0,                       lB0);
        gload_lds16(gB + (size_t)64 * KDIM + k0,   lB1);
        __syncthreads();

        bf16x8 af[4], bfr[4];
#pragma unroll
        for (int t = 0; t < 4; t++) {
            af[t]  = *(const bf16x8*)(As + (wm + t * 16 + l15) * 32 + xorv);
            bfr[t] = *(const bf16x8*)(Bs + (wn + t * 16 + l15) * 32 + xorv);
        }
#pragma unroll
        for (int mt = 0; mt < 4; mt++)
#pragma unroll
            for (int nt = 0; nt < 4; nt++)
                acc[mt][nt] = MFMA_BF16_K32(af[mt], bfr[nt], acc[mt][nt]);
    }
}

// ---------------------------------------------------------------- QKV projection
__global__ __launch_bounds__(256) void gemm_qkv(
    const bf16_t* __restrict__ A,   // [8192,768]
    const bf16_t* __restrict__ Bt,  // [2304,768]
    const float* __restrict__ bias, // [2304]
    bf16_t* __restrict__ qo, bf16_t* __restrict__ ko, f16_t* __restrict__ vo)
{
    __shared__ bf16_t As[128 * 32];
    __shared__ bf16_t Bs[128 * 32];
    const int tid = threadIdx.x, wave = tid >> 6, lane = tid & 63;
    const int quad = lane >> 4, l15 = lane & 15;
    const int m0 = blockIdx.y * 128, n0 = blockIdx.x * 128;
    f32x4 acc[4][4] = {};
    gemm_mainloop<768>(A, Bt, As, Bs, m0, n0, wave, lane, acc);

    const int wm = ((wave >> 1) << 6), wn = ((wave & 1) << 6);
#pragma unroll
    for (int nt = 0; nt < 4; nt++) {
        const int cc = n0 + wn + nt * 16 + l15;     // 0..2303
        const float bia = bias[cc];
        const int which = cc / 768;
        const int rem = cc - which * 768;
        const int h = rem >> 6, d = rem & 63;
        if (which < 2) {
            bf16_t* dst = (which == 0) ? qo : ko;
#pragma unroll
            for (int mt = 0; mt < 4; mt++) {
#pragma unroll
                for (int r = 0; r < 4; r++) {
                    const int row = m0 + wm + mt * 16 + quad * 4 + r; // 0..8191
                    const int b = row >> 12, t = row & 4095;
                    dst[((size_t)(b * 12 + h) * 4096 + t) * 64 + d] =
                        (bf16_t)(acc[mt][nt][r] + bia);
                }
            }
        } else {
            // V transposed f16: vo[((b*12+h)*64 + d)*4096 + t]
#pragma unroll
            for (int mt = 0; mt < 4; mt++) {
                const int row0 = m0 + wm + mt * 16 + quad * 4;
                const int b = row0 >> 12, t0 = row0 & 4095;
                f16x4 ov = { (f16_t)(acc[mt][nt][0] + bia),
                             (f16_t)(acc[mt][nt][1] + bia),
                             (f16_t)(acc[mt][nt][2] + bia),
                             (f16_t)(acc[mt][nt][3] + bia) };
                *(f16x4*)(vo + ((size_t)(b * 12 + h) * 64 + d) * 4096 + t0) = ov;
            }
        }
    }
}

// ---------------------------------------------------------------- output projection
__global__ __launch_bounds__(256) void gemm_proj(
    const bf16_t* __restrict__ A,   // y bf16 [8192,768]
    const bf16_t* __restrict__ Bt,  // W_proj bf16 [768,768]
    const float* __restrict__ bias, // [768]
    float* __restrict__ out)        // [8192,768] fp32
{
    __shared__ bf16_t As[128 * 32];
    __shared__ bf16_t Bs[128 * 32];
    const int tid = threadIdx.x, wave = tid >> 6, lane = tid & 63;
    const int quad = lane >> 4, l15 = lane & 15;
    const int m0 = blockIdx.y * 128, n0 = blockIdx.x * 128;
    f32x4 acc[4][4] = {};
    gemm_mainloop<768>(A, Bt, As, Bs, m0, n0, wave, lane, acc);

    const int wm = ((wave >> 1) << 6), wn = ((wave & 1) << 6);
#pragma unroll
    for (int nt = 0; nt < 4; nt++) {
        const int cc = n0 + wn + nt * 16 + l15;
        const float bia = bias[cc];
#pragma unroll
        for (int mt = 0; mt < 4; mt++) {
#pragma unroll
            for (int r = 0; r < 4; r++) {
                const int row = m0 + wm + mt * 16 + quad * 4 + r;
                out[(size_t)row * 768 + cc] = acc[mt][nt][r] + bia;
            }
        }
    }
}

// ---------------------------------------------------------------- flash attention v15
// v14 with the scratch-spill bug fixed. Round-3 evidence: WRITE_SIZE=529MB,
// VGPR dropped to 84 -> kA/kB arrays were address-taken (lambda param
// `bf16x8 kr[4]` decays to pointer) and lived in scratch (rule #20). Fix: K
// pair fragments in a named-member struct returned by value / passed by
// const-ref -- all accesses compile-time static -> pure VGPRs (~130 total,
// under the (256,3) cap of ~168). Everything else as v14: K direct global->reg
// (contiguous 2KB/wave, same addresses the old K staging issued), V
// gload_lds-staged + swizzled (scattered 32B fragments must not hit HBM,
// round-2 evidence), LDS 36.8KB, K32 PV spanning a tile pair.
#define QSCALE 0.1803368801f   // log2(e)/8
struct KPair { bf16x8 a0, a1, b0, b1; };
__global__ __launch_bounds__(256, 3) void attn_fwd(
    const bf16_t* __restrict__ qg, const bf16_t* __restrict__ kg,
    const f16_t* __restrict__ vtg, bf16_t* __restrict__ y) // y [B,T,C] bf16
{
    __shared__ __align__(16) char smem[36864];
    f16_t*  Vt0 = (f16_t*)(smem);               // 8KB each, [dim][key] swizzled
    f16_t*  Vt1 = (f16_t*)(smem + 8192);
    f16_t*  Vt2 = (f16_t*)(smem + 16384);
    f16_t*  Vt3 = (f16_t*)(smem + 24576);
    float*  RedA = (float*)(smem);              // epilogue overlays (stride 68)
    float*  RedB = (float*)(smem + 17408);
    float*  Psr  = (float*)(smem + 34816);      // [4][64]
    float*  PsT  = (float*)(smem + 35840);      // [64]

    const int tid = threadIdx.x, wave = tid >> 6, lane = tid & 63;
    const int quad = lane >> 4, l15 = lane & 15;

    const int blk = blockIdx.x;            // 0..1535
    const int xcd = blk & 7;
    const int idx = blk >> 3;              // 0..191
    const int hl  = idx % 3;
    const int qt  = idx / 3;               // 0..63
    const int bh  = xcd * 3 + hl;          // 0..23
    const int b = bh / 12, h = bh - b * 12;
    const size_t base = (size_t)bh * 4096 * 64;

    // Q fragments for all 4 qrow-chunks (B-operand: n=l15, k=quad*8+j), *log2e/8
    bf16x8 qf[4][2];
#pragma unroll
    for (int qc = 0; qc < 4; qc++) {
        const int qrow = qt * 64 + qc * 16 + l15;
        qf[qc][0] = *(const bf16x8*)(qg + base + (size_t)qrow * 64 + quad * 8);
        qf[qc][1] = *(const bf16x8*)(qg + base + (size_t)qrow * 64 + 32 + quad * 8);
#pragma unroll
        for (int j = 0; j < 8; j++) {
            qf[qc][0][j] = (bf16_t)((float)qf[qc][0][j] * QSCALE);
            qf[qc][1][j] = (bf16_t)((float)qf[qc][1][j] * QSCALE);
        }
    }

    f32x4 O[4][4] = {};      // O^T partial: [dt][qc]; dim=dt*16+quad*4+r, qrow=qc*16+l15
    float psum[4] = {};      // per-lane partial row sums (qrow = qc*16+l15)
    const f16x2 one2 = { (f16_t)1.0f, (f16_t)1.0f };

    // V staging: 8 lanes per 128B row, 16B chunks XOR-swizzled on row&7
    const int srow8 = tid >> 3;                  // 0..31 (+32 for i=1)
    const int sc8   = (tid & 7) ^ (srow8 & 7);
    const int l8 = l15 & 7;
    const int w16 = wave << 4;
    const int vslot = ((wave << 1) | (quad >> 1)) ^ l8;          // V frag 16B slot
    const int q0off = (quad & 1) * 8;

    auto stage = [&](const f16_t* vp_, f16_t* Vd) {
#pragma unroll
        for (int i = 0; i < 2; i++)
            gload_lds16(vp_ + (size_t)(i * 32 + srow8) * 4096 + sc8 * 8, Vd + (i * 256 + tid) * 8);
    };

    // K direct global->reg for a pair of tiles (t, t+1): named members only
    // (NO arrays -> no address-taken -> stays in VGPRs).
    const bf16_t* kpg = kg + base + (size_t)(w16 + l15) * 64 + quad * 8;
    auto kload = [&](int t) -> KPair {
        const bf16_t* p0 = kpg + (size_t)t * 4096;
        KPair kp;
        kp.a0 = *(const bf16x8*)(p0);
        kp.a1 = *(const bf16x8*)(p0 + 32);
        kp.b0 = *(const bf16x8*)(p0 + 4096);
        kp.b1 = *(const bf16x8*)(p0 + 4096 + 32);
        return kp;
    };

    // joint compute over a pair of 64-key tiles (A,B): QK^T+softmax per tile,
    // then one K=32 PV spanning both tiles' keys (K in regs, V from LDS).
    auto compute_pair = [&](const KPair& kp, const f16_t* vsA, const f16_t* vsB) {
        f32x4 scA[4], scB[4];
        __builtin_amdgcn_s_setprio(1);
#pragma unroll
        for (int qc = 0; qc < 4; qc++) {
            f32x4 s = {};
            s = MFMA_BF16_K32(kp.a0, qf[qc][0], s);
            s = MFMA_BF16_K32(kp.a1, qf[qc][1], s);
            scA[qc] = s;
        }
#pragma unroll
        for (int qc = 0; qc < 4; qc++) {
            f32x4 s = {};
            s = MFMA_BF16_K32(kp.b0, qf[qc][0], s);
            s = MFMA_BF16_K32(kp.b1, qf[qc][1], s);
            scB[qc] = s;
        }
        __builtin_amdgcn_s_setprio(0);
        // ---- P = exp2(S^T) for both tiles -> packed f16x8 B-operand + row sums
        f16x8 pf8[4];
#pragma unroll
        for (int qc = 0; qc < 4; qc++) {
            float a0 = __builtin_amdgcn_exp2f(scA[qc][0]);
            float a1 = __builtin_amdgcn_exp2f(scA[qc][1]);
            float a2 = __builtin_amdgcn_exp2f(scA[qc][2]);
            float a3 = __builtin_amdgcn_exp2f(scA[qc][3]);
            float b0 = __builtin_amdgcn_exp2f(scB[qc][0]);
            float b1 = __builtin_amdgcn_exp2f(scB[qc][1]);
            float b2 = __builtin_amdgcn_exp2f(scB[qc][2]);
            float b3 = __builtin_amdgcn_exp2f(scB[qc][3]);
            f16x2 loA = pkrtz(a0, a1);
            f16x2 hiA = pkrtz(a2, a3);
            f16x2 loB = pkrtz(b0, b1);
            f16x2 hiB = pkrtz(b2, b3);
            psum[qc] = __builtin_amdgcn_fdot2(loA, one2, psum[qc], false);
            psum[qc] = __builtin_amdgcn_fdot2(hiA, one2, psum[qc], false);
            psum[qc] = __builtin_amdgcn_fdot2(loB, one2, psum[qc], false);
            psum[qc] = __builtin_amdgcn_fdot2(hiB, one2, psum[qc], false);
            union { f16x8 v; f16x2 h[4]; } u;
            u.h[0] = loA; u.h[1] = hiA; u.h[2] = loB; u.h[3] = hiB;
            pf8[qc] = u.v;
        }
        // ---- O^T += V^T P with K=32 spanning both tiles: V from LDS
        __builtin_amdgcn_s_setprio(1);
#pragma unroll
        for (int dt = 0; dt < 4; dt++) {
            const char* vrA = (const char*)(vsA + (dt * 16 + l15) * 64);
            const char* vrB = (const char*)(vsB + (dt * 16 + l15) * 64);
            f16x4 vA = *(const f16x4*)(vrA + vslot * 16 + q0off);
            f16x4 vB = *(const f16x4*)(vrB + vslot * 16 + q0off);
            union { f16x8 v; f16x4 h[2]; } uv;
            uv.h[0] = vA; uv.h[1] = vB;
#pragma unroll
            for (int qc = 0; qc < 4; qc++)
                O[dt][qc] = MFMA_F16_K32(uv.v, pf8[qc], O[dt][qc]);
        }
        __builtin_amdgcn_s_setprio(0);
    };

    const f16_t* vp = vtg + base;    // +64 elems per 64-key tile
    KPair kA = kload(0);
    stage(vp, Vt0); stage(vp + 64, Vt1);
    for (int t = 0; t < 64; t += 4) {
        __syncthreads();                 // V tiles t,t+1 staged; Vt2/3 readers done
        KPair kB = kload(t + 2);
        stage(vp + 128, Vt2); stage(vp + 192, Vt3);
        compute_pair(kA, Vt0, Vt1);
        __syncthreads();                 // V tiles t+2,t+3 staged; Vt0/1 readers done
        if (t + 4 < 64) {
            kA = kload(t + 4);
            stage(vp + 256, Vt0); stage(vp + 320, Vt1);
        }
        compute_pair(kB, Vt2, Vt3);
        vp += 256;
    }

    // ================= epilogue: reduce O & psum across the 4 key-split waves
#pragma unroll
    for (int qc = 0; qc < 4; qc++) {
        psum[qc] += __shfl_xor(psum[qc], 16, 64);
        psum[qc] += __shfl_xor(psum[qc], 32, 64);
    }
    __syncthreads();   // K-loop LDS quiesced; overlay safe
    if (wave == 2) {
#pragma unroll
        for (int dt = 0; dt < 4; dt++)
#pragma unroll
            for (int qc = 0; qc < 4; qc++)
                *(f32x4*)(RedA + (qc * 16 + l15) * 68 + dt * 16 + quad * 4) = O[dt][qc];
    } else if (wave == 3) {
#pragma unroll
        for (int dt = 0; dt < 4; dt++)
#pragma unroll
            for (int qc = 0; qc < 4; qc++)
                *(f32x4*)(RedB + (qc * 16 + l15) * 68 + dt * 16 + quad * 4) = O[dt][qc];
    }
    if (quad == 0) {
#pragma unroll
        for (int qc = 0; qc < 4; qc++) Psr[wave * 64 + qc * 16 + l15] = psum[qc];
    }
    __syncthreads();   // S2
    if (wave == 0) {
#pragma unroll
        for (int dt = 0; dt < 4; dt++)
#pragma unroll
            for (int qc = 0; qc < 4; qc++)
                O[dt][qc] += *(const f32x4*)(RedA + (qc * 16 + l15) * 68 + dt * 16 + quad * 4);
    } else if (wave == 1) {
#pragma unroll
        for (int dt = 0; dt < 4; dt++)
#pragma unroll
            for (int qc = 0; qc < 4; qc++)
                O[dt][qc] += *(const f32x4*)(RedB + (qc * 16 + l15) * 68 + dt * 16 + quad * 4);
    }
    __syncthreads();   // S3
    if (wave == 1) {
#pragma unroll
        for (int dt = 0; dt < 4; dt++)
#pragma unroll
            for (int qc = 0; qc < 4; qc++)
                *(f32x4*)(RedA + (qc * 16 + l15) * 68 + dt * 16 + quad * 4) = O[dt][qc];
    } else if (wave == 3) {
        PsT[lane] = Psr[lane] + Psr[64 + lane] + Psr[128 + lane] + Psr[192 + lane];
    }
    __syncthreads();   // S4
    if (wave == 0) {
#pragma unroll
        for (int qc = 0; qc < 4; qc++) {
            const float rcp = 1.0f / PsT[qc * 16 + l15];
            const int t = qt * 64 + qc * 16 + l15;
            bf16_t* yr = y + ((size_t)b * 4096 + t) * 768 + h * 64 + quad * 4;
#pragma unroll
            for (int dt = 0; dt < 4; dt++) {
                f32x4 o4 = O[dt][qc] +
                    *(const f32x4*)(RedA + (qc * 16 + l15) * 68 + dt * 16 + quad * 4);
                bf16x4 ov = { (bf16_t)(o4[0] * rcp), (bf16_t)(o4[1] * rcp),
                              (bf16_t)(o4[2] * rcp), (bf16_t)(o4[3] * rcp) };
                *(bf16x4*)(yr + dt * 16) = ov;
            }
        }
    }
}

// ---------------------------------------------------------------- launch
extern "C" void kernel_launch(void* const* d_in, const int* in_sizes, int n_in,
                              void* d_out, int out_size, void* d_ws, size_t ws_size,
                              hipStream_t stream) {
    const float* x  = (const float*)d_in[0]; // [2,4096,768]
    const float* Wa = (const float*)d_in[1]; // [2304,768]
    const float* ba = (const float*)d_in[2]; // [2304]
    const float* Wp = (const float*)d_in[3]; // [768,768]
    const float* bp = (const float*)d_in[4]; // [768]
    float* out = (float*)d_out;              // [2,4096,768]

    char* ws = (char*)d_ws;
    bf16_t* xb  = (bf16_t*)(ws);                 //  6291456 elts
    bf16_t* Wab = (bf16_t*)(ws + 12582912);      //  1769472
    bf16_t* Wpb = (bf16_t*)(ws + 16121856);      //   589824
    bf16_t* qb  = (bf16_t*)(ws + 17301504);      //  [B,H,T,D] bf16
    bf16_t* kb  = (bf16_t*)(ws + 29884416);      //  [B,H,T,D] bf16
    f16_t*  vtb = (f16_t*)(ws + 42467328);       //  [B,H,D,T] f16 (transposed)
    bf16_t* yb  = (bf16_t*)(ws + 55050240);      //  [B,T,C] bf16

    cvt_all<<<8448, 256, 0, stream>>>(x, Wa, Wp, xb, Wab, Wpb);
    gemm_qkv <<<dim3(18, 64), 256, 0, stream>>>(xb, Wab, ba, qb, kb, vtb);
    attn_fwd <<<1536, 256, 0, stream>>>(qb, kb, vtb, yb);
    gemm_proj<<<dim3( 6, 64), 256, 0, stream>>>(yb, Wpb, bp, out);
}

// Round 5
// 427.739 us; speedup vs baseline: 1.1095x; 1.0079x over previous
//
#include <hip/hip_runtime.h>
#include <stdint.h>
#include <stddef.h>

typedef __bf16 bf16_t;
typedef bf16_t bf16x4 __attribute__((ext_vector_type(4)));
typedef bf16_t bf16x8 __attribute__((ext_vector_type(8)));
typedef float  f32x4  __attribute__((ext_vector_type(4)));
typedef _Float16 f16_t;
typedef f16_t f16x2 __attribute__((ext_vector_type(2)));
typedef f16_t f16x4 __attribute__((ext_vector_type(4)));
typedef f16_t f16x8 __attribute__((ext_vector_type(8)));
typedef __fp16 fp16x2_raw __attribute__((ext_vector_type(2)));   // cvt_pkrtz native type

__device__ __forceinline__ f16x2 pkrtz(float a, float b) {
    fp16x2_raw r = __builtin_amdgcn_cvt_pkrtz(a, b);
    union { fp16x2_raw r; f16x2 h; } u;
    u.r = r;
    return u.h;
}

#define MFMA_BF16_K32(a, b, c) __builtin_amdgcn_mfma_f32_16x16x32_bf16(a, b, c, 0, 0, 0)
#define MFMA_F16_K32(a, b, c)  __builtin_amdgcn_mfma_f32_16x16x32_f16(a, b, c, 0, 0, 0)

// ---------------------------------------------------------------- helpers
__device__ __forceinline__ void gload_lds16(const void* g, void* l) {
    __builtin_amdgcn_global_load_lds(
        (const __attribute__((address_space(1))) void*)g,
        (__attribute__((address_space(3))) void*)l,
        16, 0, 0);
}

// ---------------------------------------------------------------- fused fp32 -> bf16 casts
#define NX 1572864           // x  float4 count
#define NWA 442368           // Wa float4 count
#define NWP 147456           // Wp float4 count
__global__ void cvt_all(const float* __restrict__ x, const float* __restrict__ Wa,
                        const float* __restrict__ Wp, bf16_t* __restrict__ xb,
                        bf16_t* __restrict__ Wab, bf16_t* __restrict__ Wpb) {
    int i = blockIdx.x * blockDim.x + threadIdx.x;
    const float4* src; bf16_t* dst; int j;
    if (i < NX)            { src = (const float4*)x;  dst = xb;  j = i; }
    else if (i < NX + NWA) { src = (const float4*)Wa; dst = Wab; j = i - NX; }
    else                   { src = (const float4*)Wp; dst = Wpb; j = i - NX - NWA; }
    float4 f = src[j];
    bf16x4 o = { (bf16_t)f.x, (bf16_t)f.y, (bf16_t)f.z, (bf16_t)f.w };
    ((bf16x4*)dst)[j] = o;
}

// ---------------------------------------------------------------- GEMM main loop
template <int KDIM>
__device__ __forceinline__ void gemm_mainloop(
    const bf16_t* __restrict__ A, const bf16_t* __restrict__ Bt,
    bf16_t* As, bf16_t* Bs, int m0, int n0, int wave, int lane, f32x4 acc[4][4])
{
    const int quad = lane >> 4, l15 = lane & 15;
    const int wm = ((wave >> 1) << 6), wn = ((wave & 1) << 6);

    const int srow = (wave << 4) + (lane >> 2);                 // 0..63
    const int sw   = (((lane & 3) ^ ((srow >> 1) & 3)) << 3);   // swizzled elem offset
    const bf16_t* gA = A  + (size_t)(m0 + srow) * KDIM + sw;
    const bf16_t* gB = Bt + (size_t)(n0 + srow) * KDIM + sw;
    bf16_t* lA0 = As + wave * 512;
    bf16_t* lA1 = As + 2048 + wave * 512;
    bf16_t* lB0 = Bs + wave * 512;
    bf16_t* lB1 = Bs + 2048 + wave * 512;

    const int xorv = ((quad ^ ((l15 >> 1) & 3)) << 3);

    for (int k0 = 0; k0 < KDIM; k0 += 32) {
        __syncthreads();
        gload_lds16(gA + k0,                       lA0);
        gload_lds16(gA + (size_t)64 * KDIM + k0,   lA1);
        gload_lds16(gB + k0,                       lB0);
        gload_lds16(gB + (size_t)64 * KDIM + k0,   lB1);
        __syncthreads();

        bf16x8 af[4], bfr[4];
#pragma unroll
        for (int t = 0; t < 4; t++) {
            af[t]  = *(const bf16x8*)(As + (wm + t * 16 + l15) * 32 + xorv);
            bfr[t] = *(const bf16x8*)(Bs + (wn + t * 16 + l15) * 32 + xorv);
        }
#pragma unroll
        for (int mt = 0; mt < 4; mt++)
#pragma unroll
            for (int nt = 0; nt < 4; nt++)
                acc[mt][nt] = MFMA_BF16_K32(af[mt], bfr[nt], acc[mt][nt]);
    }
}

// ---------------------------------------------------------------- QKV projection
__global__ __launch_bounds__(256) void gemm_qkv(
    const bf16_t* __restrict__ A,   // [8192,768]
    const bf16_t* __restrict__ Bt,  // [2304,768]
    const float* __restrict__ bias, // [2304]
    bf16_t* __restrict__ qo, bf16_t* __restrict__ ko, f16_t* __restrict__ vo)
{
    __shared__ bf16_t As[128 * 32];
    __shared__ bf16_t Bs[128 * 32];
    const int tid = threadIdx.x, wave = tid >> 6, lane = tid & 63;
    const int quad = lane >> 4, l15 = lane & 15;
    const int m0 = blockIdx.y * 128, n0 = blockIdx.x * 128;
    f32x4 acc[4][4] = {};
    gemm_mainloop<768>(A, Bt, As, Bs, m0, n0, wave, lane, acc);

    const int wm = ((wave >> 1) << 6), wn = ((wave & 1) << 6);
#pragma unroll
    for (int nt = 0; nt < 4; nt++) {
        const int cc = n0 + wn + nt * 16 + l15;     // 0..2303
        const float bia = bias[cc];
        const int which = cc / 768;
        const int rem = cc - which * 768;
        const int h = rem >> 6, d = rem & 63;
        if (which < 2) {
            bf16_t* dst = (which == 0) ? qo : ko;
#pragma unroll
            for (int mt = 0; mt < 4; mt++) {
#pragma unroll
                for (int r = 0; r < 4; r++) {
                    const int row = m0 + wm + mt * 16 + quad * 4 + r; // 0..8191
                    const int b = row >> 12, t = row & 4095;
                    dst[((size_t)(b * 12 + h) * 4096 + t) * 64 + d] =
                        (bf16_t)(acc[mt][nt][r] + bia);
                }
            }
        } else {
            // V transposed f16: vo[((b*12+h)*64 + d)*4096 + t]
#pragma unroll
            for (int mt = 0; mt < 4; mt++) {
                const int row0 = m0 + wm + mt * 16 + quad * 4;
                const int b = row0 >> 12, t0 = row0 & 4095;
                f16x4 ov = { (f16_t)(acc[mt][nt][0] + bia),
                             (f16_t)(acc[mt][nt][1] + bia),
                             (f16_t)(acc[mt][nt][2] + bia),
                             (f16_t)(acc[mt][nt][3] + bia) };
                *(f16x4*)(vo + ((size_t)(b * 12 + h) * 64 + d) * 4096 + t0) = ov;
            }
        }
    }
}

// ---------------------------------------------------------------- output projection
__global__ __launch_bounds__(256) void gemm_proj(
    const bf16_t* __restrict__ A,   // y bf16 [8192,768]
    const bf16_t* __restrict__ Bt,  // W_proj bf16 [768,768]
    const float* __restrict__ bias, // [768]
    float* __restrict__ out)        // [8192,768] fp32
{
    __shared__ bf16_t As[128 * 32];
    __shared__ bf16_t Bs[128 * 32];
    const int tid = threadIdx.x, wave = tid >> 6, lane = tid & 63;
    const int quad = lane >> 4, l15 = lane & 15;
    const int m0 = blockIdx.y * 128, n0 = blockIdx.x * 128;
    f32x4 acc[4][4] = {};
    gemm_mainloop<768>(A, Bt, As, Bs, m0, n0, wave, lane, acc);

    const int wm = ((wave >> 1) << 6), wn = ((wave & 1) << 6);
#pragma unroll
    for (int nt = 0; nt < 4; nt++) {
        const int cc = n0 + wn + nt * 16 + l15;
        const float bia = bias[cc];
#pragma unroll
        for (int mt = 0; mt < 4; mt++) {
#pragma unroll
            for (int r = 0; r < 4; r++) {
                const int row = m0 + wm + mt * 16 + quad * 4 + r;
                out[(size_t)row * 768 + cc] = acc[mt][nt][r] + bia;
            }
        }
    }
}

// ---------------------------------------------------------------- flash attention v16
// Rounds 3/4 failed with IDENTICAL counters (WRITE=529MB, VGPR=84): the big
// compute lambda was OUTLINED, so its by-reference captures/params (K frags,
// O, qf) lived in scratch across a real call. gemm_mainloop in this same file
// proves the fix: __forceinline__ file-scope functions get inlined, then
// mem2reg promotes everything (it passes acc[4][4] with zero scratch). v16 =
// v15's design (K direct global->reg, V gload_lds-staged+swizzled, 36.8KB LDS,
// K32 PV over a tile pair) with ALL hot-path lambdas replaced by
// __device__ __forceinline__ functions and K frags as named bf16x8 by value.
// Register diet: one sc[4] score buffer reused for both tiles (QK-A, exp-A,
// QK-B, exp-B), P kept as two f16x4[4] halves -> peak ~160 < (256,3)'s 170.
#define QSCALE 0.1803368801f   // log2(e)/8

__device__ __forceinline__ void stage_v(const f16_t* vp_, f16_t* Vd, int srow8, int sc8, int tid) {
#pragma unroll
    for (int i = 0; i < 2; i++)
        gload_lds16(vp_ + (size_t)(i * 32 + srow8) * 4096 + sc8 * 8, Vd + (i * 256 + tid) * 8);
}

__device__ __forceinline__ void compute_pair_fn(
    bf16x8 ka0, bf16x8 ka1, bf16x8 kb0, bf16x8 kb1,
    const f16_t* vsA, const f16_t* vsB,
    const bf16x8 (&qf)[4][2], f32x4 (&O)[4][4], float (&psum)[4],
    int l15, int vslot, int q0off)
{
    const f16x2 one2 = { (f16_t)1.0f, (f16_t)1.0f };
    f32x4 sc[4];
    f16x4 pA[4], pB[4];
    // ---- S^T tile A (wave's 16 keys x 64 qrows)
    __builtin_amdgcn_s_setprio(1);
#pragma unroll
    for (int qc = 0; qc < 4; qc++) {
        f32x4 s = {};
        s = MFMA_BF16_K32(ka0, qf[qc][0], s);
        s = MFMA_BF16_K32(ka1, qf[qc][1], s);
        sc[qc] = s;
    }
    __builtin_amdgcn_s_setprio(0);
    // ---- exp tile A -> pA + psum
#pragma unroll
    for (int qc = 0; qc < 4; qc++) {
        float e0 = __builtin_amdgcn_exp2f(sc[qc][0]);
        float e1 = __builtin_amdgcn_exp2f(sc[qc][1]);
        float e2 = __builtin_amdgcn_exp2f(sc[qc][2]);
        float e3 = __builtin_amdgcn_exp2f(sc[qc][3]);
        f16x2 lo = pkrtz(e0, e1);
        f16x2 hi = pkrtz(e2, e3);
        psum[qc] = __builtin_amdgcn_fdot2(lo, one2, psum[qc], false);
        psum[qc] = __builtin_amdgcn_fdot2(hi, one2, psum[qc], false);
        union { f16x4 v; f16x2 h[2]; } u;
        u.h[0] = lo; u.h[1] = hi;
        pA[qc] = u.v;
    }
    // ---- S^T tile B (reuse sc)
    __builtin_amdgcn_s_setprio(1);
#pragma unroll
    for (int qc = 0; qc < 4; qc++) {
        f32x4 s = {};
        s = MFMA_BF16_K32(kb0, qf[qc][0], s);
        s = MFMA_BF16_K32(kb1, qf[qc][1], s);
        sc[qc] = s;
    }
    __builtin_amdgcn_s_setprio(0);
    // ---- exp tile B -> pB + psum
#pragma unroll
    for (int qc = 0; qc < 4; qc++) {
        float e0 = __builtin_amdgcn_exp2f(sc[qc][0]);
        float e1 = __builtin_amdgcn_exp2f(sc[qc][1]);
        float e2 = __builtin_amdgcn_exp2f(sc[qc][2]);
        float e3 = __builtin_amdgcn_exp2f(sc[qc][3]);
        f16x2 lo = pkrtz(e0, e1);
        f16x2 hi = pkrtz(e2, e3);
        psum[qc] = __builtin_amdgcn_fdot2(lo, one2, psum[qc], false);
        psum[qc] = __builtin_amdgcn_fdot2(hi, one2, psum[qc], false);
        union { f16x4 v; f16x2 h[2]; } u;
        u.h[0] = lo; u.h[1] = hi;
        pB[qc] = u.v;
    }
    // ---- O^T += V^T P with K=32 spanning both tiles: V from LDS
    __builtin_amdgcn_s_setprio(1);
#pragma unroll
    for (int dt = 0; dt < 4; dt++) {
        const char* vrA = (const char*)(vsA + (dt * 16 + l15) * 64);
        const char* vrB = (const char*)(vsB + (dt * 16 + l15) * 64);
        f16x4 vA = *(const f16x4*)(vrA + vslot * 16 + q0off);
        f16x4 vB = *(const f16x4*)(vrB + vslot * 16 + q0off);
        union { f16x8 v; f16x4 h[2]; } uv;
        uv.h[0] = vA; uv.h[1] = vB;
#pragma unroll
        for (int qc = 0; qc < 4; qc++) {
            union { f16x8 v; f16x4 h[2]; } up;
            up.h[0] = pA[qc]; up.h[1] = pB[qc];
            O[dt][qc] = MFMA_F16_K32(uv.v, up.v, O[dt][qc]);
        }
    }
    __builtin_amdgcn_s_setprio(0);
}

__global__ __launch_bounds__(256, 3) void attn_fwd(
    const bf16_t* __restrict__ qg, const bf16_t* __restrict__ kg,
    const f16_t* __restrict__ vtg, bf16_t* __restrict__ y) // y [B,T,C] bf16
{
    __shared__ __align__(16) char smem[36864];
    f16_t*  Vt0 = (f16_t*)(smem);               // 8KB each, [dim][key] swizzled
    f16_t*  Vt1 = (f16_t*)(smem + 8192);
    f16_t*  Vt2 = (f16_t*)(smem + 16384);
    f16_t*  Vt3 = (f16_t*)(smem + 24576);
    float*  RedA = (float*)(smem);              // epilogue overlays (stride 68)
    float*  RedB = (float*)(smem + 17408);
    float*  Psr  = (float*)(smem + 34816);      // [4][64]
    float*  PsT  = (float*)(smem + 35840);      // [64]

    const int tid = threadIdx.x, wave = tid >> 6, lane = tid & 63;
    const int quad = lane >> 4, l15 = lane & 15;

    const int blk = blockIdx.x;            // 0..1535
    const int xcd = blk & 7;
    const int idx = blk >> 3;              // 0..191
    const int hl  = idx % 3;
    const int qt  = idx / 3;               // 0..63
    const int bh  = xcd * 3 + hl;          // 0..23
    const int b = bh / 12, h = bh - b * 12;
    const size_t base = (size_t)bh * 4096 * 64;

    // Q fragments for all 4 qrow-chunks (B-operand: n=l15, k=quad*8+j), *log2e/8
    bf16x8 qf[4][2];
#pragma unroll
    for (int qc = 0; qc < 4; qc++) {
        const int qrow = qt * 64 + qc * 16 + l15;
        qf[qc][0] = *(const bf16x8*)(qg + base + (size_t)qrow * 64 + quad * 8);
        qf[qc][1] = *(const bf16x8*)(qg + base + (size_t)qrow * 64 + 32 + quad * 8);
#pragma unroll
        for (int j = 0; j < 8; j++) {
            qf[qc][0][j] = (bf16_t)((float)qf[qc][0][j] * QSCALE);
            qf[qc][1][j] = (bf16_t)((float)qf[qc][1][j] * QSCALE);
        }
    }

    f32x4 O[4][4] = {};      // O^T partial: [dt][qc]; dim=dt*16+quad*4+r, qrow=qc*16+l15
    float psum[4] = {};      // per-lane partial row sums (qrow = qc*16+l15)

    // V staging: 8 lanes per 128B row, 16B chunks XOR-swizzled on row&7
    const int srow8 = tid >> 3;                  // 0..31 (+32 for i=1)
    const int sc8   = (tid & 7) ^ (srow8 & 7);
    const int l8 = l15 & 7;
    const int w16 = wave << 4;
    const int vslot = ((wave << 1) | (quad >> 1)) ^ l8;          // V frag 16B slot
    const int q0off = (quad & 1) * 8;

    // K direct global->reg: per wave a contiguous 2KB block (16 rows x 128B)
    const bf16_t* kpg = kg + base + (size_t)(w16 + l15) * 64 + quad * 8;

    const f16_t* vp = vtg + base;    // +64 elems per 64-key tile
    bf16x8 kA0, kA1, kA2, kA3, kB0, kB1, kB2, kB3;
    {
        const bf16_t* p0 = kpg;
        kA0 = *(const bf16x8*)(p0);
        kA1 = *(const bf16x8*)(p0 + 32);
        kA2 = *(const bf16x8*)(p0 + 4096);
        kA3 = *(const bf16x8*)(p0 + 4096 + 32);
    }
    stage_v(vp, Vt0, srow8, sc8, tid); stage_v(vp + 64, Vt1, srow8, sc8, tid);
    for (int t = 0; t < 64; t += 4) {
        __syncthreads();                 // V tiles t,t+1 staged; Vt2/3 readers done
        {
            const bf16_t* p0 = kpg + (size_t)(t + 2) * 4096;
            kB0 = *(const bf16x8*)(p0);
            kB1 = *(const bf16x8*)(p0 + 32);
            kB2 = *(const bf16x8*)(p0 + 4096);
            kB3 = *(const bf16x8*)(p0 + 4096 + 32);
        }
        stage_v(vp + 128, Vt2, srow8, sc8, tid); stage_v(vp + 192, Vt3, srow8, sc8, tid);
        compute_pair_fn(kA0, kA1, kA2, kA3, Vt0, Vt1, qf, O, psum, l15, vslot, q0off);
        __syncthreads();                 // V tiles t+2,t+3 staged; Vt0/1 readers done
        if (t + 4 < 64) {
            const bf16_t* p0 = kpg + (size_t)(t + 4) * 4096;
            kA0 = *(const bf16x8*)(p0);
            kA1 = *(const bf16x8*)(p0 + 32);
            kA2 = *(const bf16x8*)(p0 + 4096);
            kA3 = *(const bf16x8*)(p0 + 4096 + 32);
            stage_v(vp + 256, Vt0, srow8, sc8, tid); stage_v(vp + 320, Vt1, srow8, sc8, tid);
        }
        compute_pair_fn(kB0, kB1, kB2, kB3, Vt2, Vt3, qf, O, psum, l15, vslot, q0off);
        vp += 256;
    }

    // ================= epilogue: reduce O & psum across the 4 key-split waves
#pragma unroll
    for (int qc = 0; qc < 4; qc++) {
        psum[qc] += __shfl_xor(psum[qc], 16, 64);
        psum[qc] += __shfl_xor(psum[qc], 32, 64);
    }
    __syncthreads();   // K-loop LDS quiesced; overlay safe
    if (wave == 2) {
#pragma unroll
        for (int dt = 0; dt < 4; dt++)
#pragma unroll
            for (int qc = 0; qc < 4; qc++)
                *(f32x4*)(RedA + (qc * 16 + l15) * 68 + dt * 16 + quad * 4) = O[dt][qc];
    } else if (wave == 3) {
#pragma unroll
        for (int dt = 0; dt < 4; dt++)
#pragma unroll
            for (int qc = 0; qc < 4; qc++)
                *(f32x4*)(RedB + (qc * 16 + l15) * 68 + dt * 16 + quad * 4) = O[dt][qc];
    }
    if (quad == 0) {
#pragma unroll
        for (int qc = 0; qc < 4; qc++) Psr[wave * 64 + qc * 16 + l15] = psum[qc];
    }
    __syncthreads();   // S2
    if (wave == 0) {
#pragma unroll
        for (int dt = 0; dt < 4; dt++)
#pragma unroll
            for (int qc = 0; qc < 4; qc++)
                O[dt][qc] += *(const f32x4*)(RedA + (qc * 16 + l15) * 68 + dt * 16 + quad * 4);
    } else if (wave == 1) {
#pragma unroll
        for (int dt = 0; dt < 4; dt++)
#pragma unroll
            for (int qc = 0; qc < 4; qc++)
                O[dt][qc] += *(const f32x4*)(RedB + (qc * 16 + l15) * 68 + dt * 16 + quad * 4);
    }
    __syncthreads();   // S3
    if (wave == 1) {
#pragma unroll
        for (int dt = 0; dt < 4; dt++)
#pragma unroll
            for (int qc = 0; qc < 4; qc++)
                *(f32x4*)(RedA + (qc * 16 + l15) * 68 + dt * 16 + quad * 4) = O[dt][qc];
    } else if (wave == 3) {
        PsT[lane] = Psr[lane] + Psr[64 + lane] + Psr[128 + lane] + Psr[192 + lane];
    }
    __syncthreads();   // S4
    if (wave == 0) {
#pragma unroll
        for (int qc = 0; qc < 4; qc++) {
            const float rcp = 1.0f / PsT[qc * 16 + l15];
            const int t = qt * 64 + qc * 16 + l15;
            bf16_t* yr = y + ((size_t)b * 4096 + t) * 768 + h * 64 + quad * 4;
#pragma unroll
            for (int dt = 0; dt < 4; dt++) {
                f32x4 o4 = O[dt][qc] +
                    *(const f32x4*)(RedA + (qc * 16 + l15) * 68 + dt * 16 + quad * 4);
                bf16x4 ov = { (bf16_t)(o4[0] * rcp), (bf16_t)(o4[1] * rcp),
                              (bf16_t)(o4[2] * rcp), (bf16_t)(o4[3] * rcp) };
                *(bf16x4*)(yr + dt * 16) = ov;
            }
        }
    }
}

// ---------------------------------------------------------------- launch
extern "C" void kernel_launch(void* const* d_in, const int* in_sizes, int n_in,
                              void* d_out, int out_size, void* d_ws, size_t ws_size,
                              hipStream_t stream) {
    const float* x  = (const float*)d_in[0]; // [2,4096,768]
    const float* Wa = (const float*)d_in[1]; // [2304,768]
    const float* ba = (const float*)d_in[2]; // [2304]
    const float* Wp = (const float*)d_in[3]; // [768,768]
    const float* bp = (const float*)d_in[4]; // [768]
    float* out = (float*)d_out;              // [2,4096,768]

    char* ws = (char*)d_ws;
    bf16_t* xb  = (bf16_t*)(ws);                 //  6291456 elts
    bf16_t* Wab = (bf16_t*)(ws + 12582912);      //  1769472
    bf16_t* Wpb = (bf16_t*)(ws + 16121856);      //   589824
    bf16_t* qb  = (bf16_t*)(ws + 17301504);      //  [B,H,T,D] bf16
    bf16_t* kb  = (bf16_t*)(ws + 29884416);      //  [B,H,T,D] bf16
    f16_t*  vtb = (f16_t*)(ws + 42467328);       //  [B,H,D,T] f16 (transposed)
    bf16_t* yb  = (bf16_t*)(ws + 55050240);      //  [B,T,C] bf16

    cvt_all<<<8448, 256, 0, stream>>>(x, Wa, Wp, xb, Wab, Wpb);
    gemm_qkv <<<dim3(18, 64), 256, 0, stream>>>(xb, Wab, ba, qb, kb, vtb);
    attn_fwd <<<1536, 256, 0, stream>>>(qb, kb, vtb, yb);
    gemm_proj<<<dim3( 6, 64), 256, 0, stream>>>(yb, Wpb, bp, out);
}

// Round 6
// 270.499 us; speedup vs baseline: 1.7544x; 1.5813x over previous
//
#include <hip/hip_runtime.h>
#include <stdint.h>
#include <stddef.h>

typedef __bf16 bf16_t;
typedef bf16_t bf16x4 __attribute__((ext_vector_type(4)));
typedef bf16_t bf16x8 __attribute__((ext_vector_type(8)));
typedef float  f32x4  __attribute__((ext_vector_type(4)));
typedef _Float16 f16_t;
typedef f16_t f16x2 __attribute__((ext_vector_type(2)));
typedef f16_t f16x4 __attribute__((ext_vector_type(4)));
typedef f16_t f16x8 __attribute__((ext_vector_type(8)));
typedef __fp16 fp16x2_raw __attribute__((ext_vector_type(2)));   // cvt_pkrtz native type

__device__ __forceinline__ f16x2 pkrtz(float a, float b) {
    fp16x2_raw r = __builtin_amdgcn_cvt_pkrtz(a, b);
    union { fp16x2_raw r; f16x2 h; } u;
    u.r = r;
    return u.h;
}

#define MFMA_BF16_K32(a, b, c) __builtin_amdgcn_mfma_f32_16x16x32_bf16(a, b, c, 0, 0, 0)
#define MFMA_F16_K32(a, b, c)  __builtin_amdgcn_mfma_f32_16x16x32_f16(a, b, c, 0, 0, 0)

// ---------------------------------------------------------------- helpers
__device__ __forceinline__ void gload_lds16(const void* g, void* l) {
    __builtin_amdgcn_global_load_lds(
        (const __attribute__((address_space(1))) void*)g,
        (__attribute__((address_space(3))) void*)l,
        16, 0, 0);
}

// ---------------------------------------------------------------- fused fp32 -> bf16 casts
#define NX 1572864           // x  float4 count
#define NWA 442368           // Wa float4 count
#define NWP 147456           // Wp float4 count
__global__ void cvt_all(const float* __restrict__ x, const float* __restrict__ Wa,
                        const float* __restrict__ Wp, bf16_t* __restrict__ xb,
                        bf16_t* __restrict__ Wab, bf16_t* __restrict__ Wpb) {
    int i = blockIdx.x * blockDim.x + threadIdx.x;
    const float4* src; bf16_t* dst; int j;
    if (i < NX)            { src = (const float4*)x;  dst = xb;  j = i; }
    else if (i < NX + NWA) { src = (const float4*)Wa; dst = Wab; j = i - NX; }
    else                   { src = (const float4*)Wp; dst = Wpb; j = i - NX - NWA; }
    float4 f = src[j];
    bf16x4 o = { (bf16_t)f.x, (bf16_t)f.y, (bf16_t)f.z, (bf16_t)f.w };
    ((bf16x4*)dst)[j] = o;
}

// ---------------------------------------------------------------- GEMM main loop
template <int KDIM>
__device__ __forceinline__ void gemm_mainloop(
    const bf16_t* __restrict__ A, const bf16_t* __restrict__ Bt,
    bf16_t* As, bf16_t* Bs, int m0, int n0, int wave, int lane, f32x4 acc[4][4])
{
    const int quad = lane >> 4, l15 = lane & 15;
    const int wm = ((wave >> 1) << 6), wn = ((wave & 1) << 6);

    const int srow = (wave << 4) + (lane >> 2);                 // 0..63
    const int sw   = (((lane & 3) ^ ((srow >> 1) & 3)) << 3);   // swizzled elem offset
    const bf16_t* gA = A  + (size_t)(m0 + srow) * KDIM + sw;
    const bf16_t* gB = Bt + (size_t)(n0 + srow) * KDIM + sw;
    bf16_t* lA0 = As + wave * 512;
    bf16_t* lA1 = As + 2048 + wave * 512;
    bf16_t* lB0 = Bs + wave * 512;
    bf16_t* lB1 = Bs + 2048 + wave * 512;

    const int xorv = ((quad ^ ((l15 >> 1) & 3)) << 3);

    for (int k0 = 0; k0 < KDIM; k0 += 32) {
        __syncthreads();
        gload_lds16(gA + k0,                       lA0);
        gload_lds16(gA + (size_t)64 * KDIM + k0,   lA1);
        gload_lds16(gB + k0,                       lB0);
        gload_lds16(gB + (size_t)64 * KDIM + k0,   lB1);
        __syncthreads();

        bf16x8 af[4], bfr[4];
#pragma unroll
        for (int t = 0; t < 4; t++) {
            af[t]  = *(const bf16x8*)(As + (wm + t * 16 + l15) * 32 + xorv);
            bfr[t] = *(const bf16x8*)(Bs + (wn + t * 16 + l15) * 32 + xorv);
        }
#pragma unroll
        for (int mt = 0; mt < 4; mt++)
#pragma unroll
            for (int nt = 0; nt < 4; nt++)
                acc[mt][nt] = MFMA_BF16_K32(af[mt], bfr[nt], acc[mt][nt]);
    }
}

// ---------------------------------------------------------------- QKV projection
__global__ __launch_bounds__(256) void gemm_qkv(
    const bf16_t* __restrict__ A,   // [8192,768]
    const bf16_t* __restrict__ Bt,  // [2304,768]
    const float* __restrict__ bias, // [2304]
    bf16_t* __restrict__ qo, bf16_t* __restrict__ ko, f16_t* __restrict__ vo)
{
    __shared__ bf16_t As[128 * 32];
    __shared__ bf16_t Bs[128 * 32];
    const int tid = threadIdx.x, wave = tid >> 6, lane = tid & 63;
    const int quad = lane >> 4, l15 = lane & 15;
    const int m0 = blockIdx.y * 128, n0 = blockIdx.x * 128;
    f32x4 acc[4][4] = {};
    gemm_mainloop<768>(A, Bt, As, Bs, m0, n0, wave, lane, acc);

    const int wm = ((wave >> 1) << 6), wn = ((wave & 1) << 6);
#pragma unroll
    for (int nt = 0; nt < 4; nt++) {
        const int cc = n0 + wn + nt * 16 + l15;     // 0..2303
        const float bia = bias[cc];
        const int which = cc / 768;
        const int rem = cc - which * 768;
        const int h = rem >> 6, d = rem & 63;
        if (which < 2) {
            bf16_t* dst = (which == 0) ? qo : ko;
#pragma unroll
            for (int mt = 0; mt < 4; mt++) {
#pragma unroll
                for (int r = 0; r < 4; r++) {
                    const int row = m0 + wm + mt * 16 + quad * 4 + r; // 0..8191
                    const int b = row >> 12, t = row & 4095;
                    dst[((size_t)(b * 12 + h) * 4096 + t) * 64 + d] =
                        (bf16_t)(acc[mt][nt][r] + bia);
                }
            }
        } else {
            // V transposed f16: vo[((b*12+h)*64 + d)*4096 + t]
#pragma unroll
            for (int mt = 0; mt < 4; mt++) {
                const int row0 = m0 + wm + mt * 16 + quad * 4;
                const int b = row0 >> 12, t0 = row0 & 4095;
                f16x4 ov = { (f16_t)(acc[mt][nt][0] + bia),
                             (f16_t)(acc[mt][nt][1] + bia),
                             (f16_t)(acc[mt][nt][2] + bia),
                             (f16_t)(acc[mt][nt][3] + bia) };
                *(f16x4*)(vo + ((size_t)(b * 12 + h) * 64 + d) * 4096 + t0) = ov;
            }
        }
    }
}

// ---------------------------------------------------------------- output projection
__global__ __launch_bounds__(256) void gemm_proj(
    const bf16_t* __restrict__ A,   // y bf16 [8192,768]
    const bf16_t* __restrict__ Bt,  // W_proj bf16 [768,768]
    const float* __restrict__ bias, // [768]
    float* __restrict__ out)        // [8192,768] fp32
{
    __shared__ bf16_t As[128 * 32];
    __shared__ bf16_t Bs[128 * 32];
    const int tid = threadIdx.x, wave = tid >> 6, lane = tid & 63;
    const int quad = lane >> 4, l15 = lane & 15;
    const int m0 = blockIdx.y * 128, n0 = blockIdx.x * 128;
    f32x4 acc[4][4] = {};
    gemm_mainloop<768>(A, Bt, As, Bs, m0, n0, wave, lane, acc);

    const int wm = ((wave >> 1) << 6), wn = ((wave & 1) << 6);
#pragma unroll
    for (int nt = 0; nt < 4; nt++) {
        const int cc = n0 + wn + nt * 16 + l15;
        const float bia = bias[cc];
#pragma unroll
        for (int mt = 0; mt < 4; mt++) {
#pragma unroll
            for (int r = 0; r < 4; r++) {
                const int row = m0 + wm + mt * 16 + quad * 4 + r;
                out[(size_t)row * 768 + cc] = acc[mt][nt][r] + bia;
            }
        }
    }
}

// ---------------------------------------------------------------- flash attention v17
// v12 (best verified: 131.7us, K32 PV over a tile pair, K+V LDS-staged) with
// ASYMMETRIC buffering to regain occupancy. Rounds 3-5 (direct-K regs)
// abandoned: 3 distinct implementations all hit un-fixable scratch traffic.
// Phase insight: K LDS is read only at compute START (8 ds_read_b128 -> kf
// regs), V only at compute END (PV). So: K pair-double-buffered (2x16KB,
// staged during prev compute), V SINGLE pair buffer (16KB) restaged right
// after the post-compute barrier and consumed ~400cy later at the next PV,
// hidden under QK+exp. LDS 64KB -> 48KB => 3 blocks/CU (was 2). Cost: 2nd
// barrier per pair (mid-compute, publishes V[p+1]) -- 65 barriers, the v11
// count. All math/swizzles/epilogue byte-identical to v12.
// Drain proof: every gload_lds batch crosses >=1 __syncthreads (full vmcnt
// drain) before first read; every overwrite follows its last reader's barrier.
#define QSCALE 0.1803368801f   // log2(e)/8
__global__ __launch_bounds__(256, 3) void attn_fwd(
    const bf16_t* __restrict__ qg, const bf16_t* __restrict__ kg,
    const f16_t* __restrict__ vtg, bf16_t* __restrict__ y) // y [B,T,C] bf16
{
    __shared__ __align__(16) char smem[49152];
    bf16_t* Ks0 = (bf16_t*)(smem);              // 8KB each, [key][dim] swizzled
    bf16_t* Ks1 = (bf16_t*)(smem + 8192);       // slot0 = pair tiles A,B
    bf16_t* Ks2 = (bf16_t*)(smem + 16384);      // slot1 = pair tiles A,B
    bf16_t* Ks3 = (bf16_t*)(smem + 24576);
    f16_t*  Vt0 = (f16_t*)(smem + 32768);       // single V pair: tiles A,B
    f16_t*  Vt1 = (f16_t*)(smem + 40960);
    float*  RedA = (float*)(smem);              // epilogue overlays (stride 68)
    float*  RedB = (float*)(smem + 17408);
    float*  Psr  = (float*)(smem + 34816);      // [4][64]
    float*  PsT  = (float*)(smem + 35840);      // [64]

    const int tid = threadIdx.x, wave = tid >> 6, lane = tid & 63;
    const int quad = lane >> 4, l15 = lane & 15;

    const int blk = blockIdx.x;            // 0..1535
    const int xcd = blk & 7;
    const int idx = blk >> 3;              // 0..191
    const int hl  = idx % 3;
    const int qt  = idx / 3;               // 0..63
    const int bh  = xcd * 3 + hl;          // 0..23
    const int b = bh / 12, h = bh - b * 12;
    const size_t base = (size_t)bh * 4096 * 64;

    // Q fragments for all 4 qrow-chunks (B-operand: n=l15, k=quad*8+j), *log2e/8
    bf16x8 qf[4][2];
#pragma unroll
    for (int qc = 0; qc < 4; qc++) {
        const int qrow = qt * 64 + qc * 16 + l15;
        qf[qc][0] = *(const bf16x8*)(qg + base + (size_t)qrow * 64 + quad * 8);
        qf[qc][1] = *(const bf16x8*)(qg + base + (size_t)qrow * 64 + 32 + quad * 8);
#pragma unroll
        for (int j = 0; j < 8; j++) {
            qf[qc][0][j] = (bf16_t)((float)qf[qc][0][j] * QSCALE);
            qf[qc][1][j] = (bf16_t)((float)qf[qc][1][j] * QSCALE);
        }
    }

    f32x4 O[4][4] = {};      // O^T partial: [dt][qc]; dim=dt*16+quad*4+r, qrow=qc*16+l15
    float psum[4] = {};      // per-lane partial row sums (qrow = qc*16+l15)
    const f16x2 one2 = { (f16_t)1.0f, (f16_t)1.0f };

    // staging: 8 lanes per 128B row, 16B chunks XOR-swizzled on row&7
    const int srow8 = tid >> 3;                  // 0..31 (+32 for i=1)
    const int sc8   = (tid & 7) ^ (srow8 & 7);
    const int l8 = l15 & 7;
    const int w16 = wave << 4;
    const int ksoff = (quad ^ l8) << 3;                          // K frag slot (elems)
    const int vslot = ((wave << 1) | (quad >> 1)) ^ l8;          // V frag 16B slot
    const int q0off = (quad & 1) * 8;

    auto stage_k = [&](const bf16_t* kp_, bf16_t* Kd) {
#pragma unroll
        for (int i = 0; i < 2; i++)
            gload_lds16(kp_ + (i * 32 + srow8) * 64 + sc8 * 8, Kd + (i * 256 + tid) * 8);
    };
    auto stage_v = [&](const f16_t* vp_, f16_t* Vd) {
#pragma unroll
        for (int i = 0; i < 2; i++)
            gload_lds16(vp_ + (size_t)(i * 32 + srow8) * 4096 + sc8 * 8, Vd + (i * 256 + tid) * 8);
    };

    // joint compute over a pair of 64-key tiles (A,B): QK^T+softmax per tile,
    // then one K=32 PV spanning both tiles' keys. Contains the mid-compute
    // barrier (after kf reads + QK + exp) that publishes the V restage.
    auto compute_pair = [&](const bf16_t* ksA, const bf16_t* ksB) {
        // ---- S^T tile A then tile B (wave's 16 keys x 64 qrows each)
        const bf16_t* krA = ksA + (w16 + l15) * 64;
        const bf16_t* krB = ksB + (w16 + l15) * 64;
        bf16x8 kfA0 = *(const bf16x8*)(krA + ksoff);
        bf16x8 kfA1 = *(const bf16x8*)(krA + (ksoff ^ 32));
        bf16x8 kfB0 = *(const bf16x8*)(krB + ksoff);
        bf16x8 kfB1 = *(const bf16x8*)(krB + (ksoff ^ 32));
        f32x4 scA[4], scB[4];
        __builtin_amdgcn_s_setprio(1);
#pragma unroll
        for (int qc = 0; qc < 4; qc++) {
            f32x4 s = {};
            s = MFMA_BF16_K32(kfA0, qf[qc][0], s);
            s = MFMA_BF16_K32(kfA1, qf[qc][1], s);
            scA[qc] = s;
        }
#pragma unroll
        for (int qc = 0; qc < 4; qc++) {
            f32x4 s = {};
            s = MFMA_BF16_K32(kfB0, qf[qc][0], s);
            s = MFMA_BF16_K32(kfB1, qf[qc][1], s);
            scB[qc] = s;
        }
        __builtin_amdgcn_s_setprio(0);
        // ---- P = exp2(S^T) for both tiles -> packed f16x8 B-operand + row sums
        f16x8 pf8[4];
#pragma unroll
        for (int qc = 0; qc < 4; qc++) {
            float a0 = __builtin_amdgcn_exp2f(scA[qc][0]);
            float a1 = __builtin_amdgcn_exp2f(scA[qc][1]);
            float a2 = __builtin_amdgcn_exp2f(scA[qc][2]);
            float a3 = __builtin_amdgcn_exp2f(scA[qc][3]);
            float b0 = __builtin_amdgcn_exp2f(scB[qc][0]);
            float b1 = __builtin_amdgcn_exp2f(scB[qc][1]);
            float b2 = __builtin_amdgcn_exp2f(scB[qc][2]);
            float b3 = __builtin_amdgcn_exp2f(scB[qc][3]);
            f16x2 loA = pkrtz(a0, a1);
            f16x2 hiA = pkrtz(a2, a3);
            f16x2 loB = pkrtz(b0, b1);
            f16x2 hiB = pkrtz(b2, b3);
            psum[qc] = __builtin_amdgcn_fdot2(loA, one2, psum[qc], false);
            psum[qc] = __builtin_amdgcn_fdot2(hiA, one2, psum[qc], false);
            psum[qc] = __builtin_amdgcn_fdot2(loB, one2, psum[qc], false);
            psum[qc] = __builtin_amdgcn_fdot2(hiB, one2, psum[qc], false);
            union { f16x8 v; f16x2 h[4]; } u;
            u.h[0] = loA; u.h[1] = hiA; u.h[2] = loB; u.h[3] = hiB;
            pf8[qc] = u.v;
        }
        // ---- barrier1: publishes this pair's V restage (issued last iter);
        //      also confirms all waves are done with the K slot's kf reads.
        __syncthreads();
        // ---- O^T += V^T P with K=32 spanning both tiles: V from LDS
        __builtin_amdgcn_s_setprio(1);
#pragma unroll
        for (int dt = 0; dt < 4; dt++) {
            const char* vrA = (const char*)(Vt0 + (dt * 16 + l15) * 64);
            const char* vrB = (const char*)(Vt1 + (dt * 16 + l15) * 64);
            f16x4 vA = *(const f16x4*)(vrA + vslot * 16 + q0off);
            f16x4 vB = *(const f16x4*)(vrB + vslot * 16 + q0off);
            union { f16x8 v; f16x4 h[2]; } uv;
            uv.h[0] = vA; uv.h[1] = vB;
#pragma unroll
            for (int qc = 0; qc < 4; qc++)
                O[dt][qc] = MFMA_F16_K32(uv.v, pf8[qc], O[dt][qc]);
        }
        __builtin_amdgcn_s_setprio(0);
    };

    const bf16_t* kp = kg + base;    // +4096 elems (8KB) per 64-key tile
    const f16_t*  vp = vtg + base;   // +64 elems per tile
    // prologue: pair 0 (K slot0 + V), drain, then pair 1 K (slot1) in flight
    stage_k(kp, Ks0); stage_k(kp + 4096, Ks1);
    stage_v(vp, Vt0); stage_v(vp + 64, Vt1);
    __syncthreads();
    stage_k(kp + 8192, Ks2); stage_k(kp + 12288, Ks3);
    for (int p = 0; p < 32; p++) {
        // compute pair p from K slot (p&1); barrier1 inside (pre-PV)
        compute_pair((p & 1) ? Ks2 : Ks0, (p & 1) ? Ks3 : Ks1);
        __syncthreads();   // barrier2: V + K-slot readers done; restage safe
        if (p < 30) {      // K[p+2] -> slot (p&1) (just-freed)
            const bf16_t* kn = kp + (size_t)(p + 2) * 8192;
            stage_k(kn, (p & 1) ? Ks2 : Ks0);
            stage_k(kn + 4096, (p & 1) ? Ks3 : Ks1);
        }
        if (p < 31) {      // V[p+1] -> the single V pair buffer
            const f16_t* vn = vp + (size_t)(p + 1) * 128;
            stage_v(vn, Vt0); stage_v(vn + 64, Vt1);
        }
    }

    // ================= epilogue: reduce O & psum across the 4 key-split waves
#pragma unroll
    for (int qc = 0; qc < 4; qc++) {
        psum[qc] += __shfl_xor(psum[qc], 16, 64);
        psum[qc] += __shfl_xor(psum[qc], 32, 64);
    }
    __syncthreads();   // K-loop LDS quiesced; overlay safe
    if (wave == 2) {
#pragma unroll
        for (int dt = 0; dt < 4; dt++)
#pragma unroll
            for (int qc = 0; qc < 4; qc++)
                *(f32x4*)(RedA + (qc * 16 + l15) * 68 + dt * 16 + quad * 4) = O[dt][qc];
    } else if (wave == 3) {
#pragma unroll
        for (int dt = 0; dt < 4; dt++)
#pragma unroll
            for (int qc = 0; qc < 4; qc++)
                *(f32x4*)(RedB + (qc * 16 + l15) * 68 + dt * 16 + quad * 4) = O[dt][qc];
    }
    if (quad == 0) {
#pragma unroll
        for (int qc = 0; qc < 4; qc++) Psr[wave * 64 + qc * 16 + l15] = psum[qc];
    }
    __syncthreads();   // S2
    if (wave == 0) {
#pragma unroll
        for (int dt = 0; dt < 4; dt++)
#pragma unroll
            for (int qc = 0; qc < 4; qc++)
                O[dt][qc] += *(const f32x4*)(RedA + (qc * 16 + l15) * 68 + dt * 16 + quad * 4);
    } else if (wave == 1) {
#pragma unroll
        for (int dt = 0; dt < 4; dt++)
#pragma unroll
            for (int qc = 0; qc < 4; qc++)
                O[dt][qc] += *(const f32x4*)(RedB + (qc * 16 + l15) * 68 + dt * 16 + quad * 4);
    }
    __syncthreads();   // S3
    if (wave == 1) {
#pragma unroll
        for (int dt = 0; dt < 4; dt++)
#pragma unroll
            for (int qc = 0; qc < 4; qc++)
                *(f32x4*)(RedA + (qc * 16 + l15) * 68 + dt * 16 + quad * 4) = O[dt][qc];
    } else if (wave == 3) {
        PsT[lane] = Psr[lane] + Psr[64 + lane] + Psr[128 + lane] + Psr[192 + lane];
    }
    __syncthreads();   // S4
    if (wave == 0) {
#pragma unroll
        for (int qc = 0; qc < 4; qc++) {
            const float rcp = 1.0f / PsT[qc * 16 + l15];
            const int t = qt * 64 + qc * 16 + l15;
            bf16_t* yr = y + ((size_t)b * 4096 + t) * 768 + h * 64 + quad * 4;
#pragma unroll
            for (int dt = 0; dt < 4; dt++) {
                f32x4 o4 = O[dt][qc] +
                    *(const f32x4*)(RedA + (qc * 16 + l15) * 68 + dt * 16 + quad * 4);
                bf16x4 ov = { (bf16_t)(o4[0] * rcp), (bf16_t)(o4[1] * rcp),
                              (bf16_t)(o4[2] * rcp), (bf16_t)(o4[3] * rcp) };
                *(bf16x4*)(yr + dt * 16) = ov;
            }
        }
    }
}

// ---------------------------------------------------------------- launch
extern "C" void kernel_launch(void* const* d_in, const int* in_sizes, int n_in,
                              void* d_out, int out_size, void* d_ws, size_t ws_size,
                              hipStream_t stream) {
    const float* x  = (const float*)d_in[0]; // [2,4096,768]
    const float* Wa = (const float*)d_in[1]; // [2304,768]
    const float* ba = (const float*)d_in[2]; // [2304]
    const float* Wp = (const float*)d_in[3]; // [768,768]
    const float* bp = (const float*)d_in[4]; // [768]
    float* out = (float*)d_out;              // [2,4096,768]

    char* ws = (char*)d_ws;
    bf16_t* xb  = (bf16_t*)(ws);                 //  6291456 elts
    bf16_t* Wab = (bf16_t*)(ws + 12582912);      //  1769472
    bf16_t* Wpb = (bf16_t*)(ws + 16121856);      //   589824
    bf16_t* qb  = (bf16_t*)(ws + 17301504);      //  [B,H,T,D] bf16
    bf16_t* kb  = (bf16_t*)(ws + 29884416);      //  [B,H,T,D] bf16
    f16_t*  vtb = (f16_t*)(ws + 42467328);       //  [B,H,D,T] f16 (transposed)
    bf16_t* yb  = (bf16_t*)(ws + 55050240);      //  [B,T,C] bf16

    cvt_all<<<8448, 256, 0, stream>>>(x, Wa, Wp, xb, Wab, Wpb);
    gemm_qkv <<<dim3(18, 64), 256, 0, stream>>>(xb, Wab, ba, qb, kb, vtb);
    attn_fwd <<<1536, 256, 0, stream>>>(qb, kb, vtb, yb);
    gemm_proj<<<dim3( 6, 64), 256, 0, stream>>>(yb, Wpb, bp, out);
}